// Round 21
// baseline (1387.593 us; speedup 1.0000x reference)
//
#include <hip/hip_runtime.h>
#include <hip/hip_bf16.h>

__device__ __forceinline__ float eluf(float x){ return x > 0.f ? x : expm1f(x); }

typedef __attribute__((ext_vector_type(8))) short bf16x8;
typedef __attribute__((ext_vector_type(4))) float f32x4;

__device__ __forceinline__ unsigned int bf16r(float f){
  unsigned int u = __float_as_uint(f);
  return (u + 0x7FFFu + ((u >> 16) & 1u)) >> 16;   // RNE
}

// LDS row stride helper
constexpr int pad_stride(int wp){
  int s = (wp + 3) & ~3;
  return (s % 8 == 0) ? s + 4 : s;
}

// ---------------- naive 3x3 pad-1 conv (kept only for tiny conv4) ----------------
__global__ void conv3x3_kernel(const float* __restrict__ in, const float* __restrict__ w,
                               const float* __restrict__ bias, float* __restrict__ out,
                               int B, int Cin, int Cout, int H, int W, int Ctot, int ooff, int act)
{
  int idx = blockIdx.x*256 + threadIdx.x;
  int total = B*Cout*H*W;
  if (idx >= total) return;
  int x = idx % W; int t = idx / W;
  int y = t % H;   t /= H;
  int o = t % Cout; int b = t / Cout;
  float acc = bias ? bias[o] : 0.f;
  const float* wp = w + (long long)o*Cin*9;
  for (int c = 0; c < Cin; c++){
    const float* ip = in + (long long)(b*Cin + c)*H*W;
    const float* wc = wp + c*9;
    #pragma unroll
    for (int ky = 0; ky < 3; ky++){
      int iy = y + ky - 1; if ((unsigned)iy >= (unsigned)H) continue;
      #pragma unroll
      for (int kx = 0; kx < 3; kx++){
        int ix = x + kx - 1; if ((unsigned)ix >= (unsigned)W) continue;
        acc += wc[ky*3+kx] * ip[iy*W + ix];
      }
    }
  }
  if (act == 1) acc = 1.f/(1.f + expf(-acc));
  out[(((long long)b*Ctot + ooff + o)*H + y)*W + x] = acc;
}

// ---------------- conv1: 2->64, 28x28, fused bn-stats ----------------
__global__ __launch_bounds__(256)
void conv1_tiled(const float* __restrict__ in, const float* __restrict__ w,
                 const float* __restrict__ bias, float* __restrict__ out,
                 float* __restrict__ sum, float* __restrict__ sq)
{
  constexpr int WPL = pad_stride(30);   // 36
  __shared__ __align__(16) float img[2][30*WPL];
  __shared__ float wl[2][8*9];
  const int b = blockIdx.x, o0 = blockIdx.y*8, t = threadIdx.x;
  const int ol = t & 7, y = t >> 3;
  for (int idx = t; idx < 2*30*WPL; idx += 256) ((float*)img)[idx] = 0.f;
  __syncthreads();
  for (int idx = t; idx < 2*784; idx += 256){
    int cl = idx/784, r = idx%784;
    img[cl][(r/28 + 1)*WPL + (r%28) + 1] = in[((long long)b*2)*784 + idx];
  }
  if (t < 144){
    int cl = t/72, r = t%72;
    wl[cl][r] = w[(((long long)(o0 + r/9))*2 + cl)*9 + (r%9)];
  }
  __syncthreads();
  const bool active = (y < 28);
  float acc[28];
  #pragma unroll
  for (int x = 0; x < 28; x++) acc[x] = 0.f;
  if (active){
    for (int cl = 0; cl < 2; cl++){
      #pragma unroll
      for (int ky = 0; ky < 3; ky++){
        const float* row = &img[cl][(y+ky)*WPL];
        float rin[30];
        #pragma unroll
        for (int q = 0; q < 7; q++){
          float4 v = ((const float4*)row)[q];
          rin[4*q+0]=v.x; rin[4*q+1]=v.y; rin[4*q+2]=v.z; rin[4*q+3]=v.w;
        }
        rin[28] = row[28]; rin[29] = row[29];
        #pragma unroll
        for (int kx = 0; kx < 3; kx++){
          float wv = wl[cl][ol*9 + ky*3 + kx];
          #pragma unroll
          for (int x = 0; x < 28; x++) acc[x] += wv * rin[x+kx];
        }
      }
    }
  }
  const int og = o0 + ol;
  float sv = 0.f, qv = 0.f;
  if (active){
    float bv = bias[og];
    float* po = out + (((long long)b*64 + og)*28 + y)*28;
    #pragma unroll
    for (int x = 0; x < 28; x++){
      float v = acc[x] + bv;
      po[x] = v;
      sv += v; qv += v*v;
    }
  }
  #pragma unroll
  for (int d = 32; d >= 8; d >>= 1){
    sv += __shfl_down(sv, d);
    qv += __shfl_down(qv, d);
  }
  if ((t & 63) < 8){ atomicAdd(&sum[og], sv); atomicAdd(&sq[og], qv); }
}

// ---------------- tiled 3x3 conv, CS=1, 16-o tile (for small Cout convs) ----------------
template<int HIN,int WIN,int HOUT,int WOUT,int PAD>
__global__ __launch_bounds__(256)
void conv_tiled(const float* __restrict__ in, const float* __restrict__ w,
                const float* __restrict__ bias, float* __restrict__ out,
                int Cin, int Cout, int Ctot, int ooff, int act)
{
  constexpr int HP = HIN + 2*PAD, WP = WIN + 2*PAD, WPL = pad_stride(WP);
  constexpr int NR = WOUT + 2;
  __shared__ __align__(16) float img[HP*WPL];
  __shared__ float wl[16*9];
  const int b  = blockIdx.x;
  const int o0 = blockIdx.y * 16;
  const int t  = threadIdx.x;
  const int ol = t & 15, y = t >> 4;
  const bool act_th = (y < HOUT) && (o0 + ol < Cout);
  float acc[WOUT];
  #pragma unroll
  for (int x = 0; x < WOUT; x++) acc[x] = 0.f;
  for (int idx = t; idx < HP*WPL; idx += 256) img[idx] = 0.f;
  const long long inb = (long long)b*Cin*HIN*WIN;
  for (int c = 0; c < Cin; c++){
    __syncthreads();
    for (int idx = t; idx < HIN*WIN; idx += 256){
      int iy = idx / WIN, ix = idx % WIN;
      img[(iy+PAD)*WPL + (ix+PAD)] = in[inb + (long long)c*HIN*WIN + idx];
    }
    if (t < 144){
      int oo = t / 9, kk = t % 9;
      int og = o0 + oo;
      wl[t] = (og < Cout) ? w[((long long)og*Cin + c)*9 + kk] : 0.f;
    }
    __syncthreads();
    if (act_th){
      #pragma unroll
      for (int ky = 0; ky < 3; ky++){
        const float* row = &img[(y+ky)*WPL];
        float rin[NR];
        #pragma unroll
        for (int q = 0; q < NR/4; q++){
          float4 v = ((const float4*)row)[q];
          rin[4*q+0]=v.x; rin[4*q+1]=v.y; rin[4*q+2]=v.z; rin[4*q+3]=v.w;
        }
        #pragma unroll
        for (int x = (NR/4)*4; x < NR; x++) rin[x] = row[x];
        #pragma unroll
        for (int kx = 0; kx < 3; kx++){
          float wv = wl[ol*9 + ky*3 + kx];
          #pragma unroll
          for (int x = 0; x < WOUT; x++) acc[x] += wv * rin[x+kx];
        }
      }
    }
  }
  if (act_th){
    int og = o0 + ol;
    float bv = bias[og];
    #pragma unroll
    for (int x = 0; x < WOUT; x++){
      float v = acc[x] + bv;
      if (act == 1) v = 1.f/(1.f + expf(-v));
      else if (act == 2) v = eluf(v);
      out[(((long long)b*Ctot + ooff + og)*HOUT + y)*WOUT + x] = v;
    }
  }
}

// ---------------- conv weight transpose: -> wT[c][o*9+kk] (flip for transpose-conv) ----------------
__global__ void wtrans3_kernel(const float* __restrict__ w, float* __restrict__ wT,
                               int Cin, int Cout, int flip)
{
  int n = Cin*Cout*9;
  int idx = blockIdx.x*256 + threadIdx.x;
  if (idx >= n) return;
  int c  = idx / (Cout*9);
  int r  = idx % (Cout*9);
  int o  = r / 9, kk = r % 9;
  float v;
  if (flip) v = w[((long long)c*Cout + o)*9 + (2 - kk/3)*3 + (2 - kk%3)];
  else      v = w[((long long)o*Cin + c)*9 + kk];
  wT[idx] = v;
}

// ---------------- conv3 weights -> bf16 wb[kk][o][c] ----------------
__global__ void wconv3_bf16_kernel(const float* __restrict__ w, unsigned short* __restrict__ wb)
{
  int idx = blockIdx.x*256 + threadIdx.x;
  if (idx >= 147456) return;
  int kk = idx >> 14;
  int r  = idx & 16383;
  int o  = r >> 7, c = r & 127;
  wb[idx] = (unsigned short)bf16r(w[((long long)o*128 + c)*9 + kk]);
}

// ---------------- conv3 via bf16 MFMA (shift-decomposed implicit GEMM) ----------------
__global__ __launch_bounds__(256)
void conv3_mfma(const float* __restrict__ in, const unsigned short* __restrict__ wb,
                const float* __restrict__ bias, float* __restrict__ out,
                float* __restrict__ sum, float* __restrict__ sq)
{
  constexpr int RS = 88;                   // u16 per hp row (64 ch + 24 pad) = 176 B
  __shared__ unsigned short img[256*RS];
  __shared__ float sred[16], qred[16];
  const int b  = blockIdx.x;
  const int o0 = blockIdx.y * 16;
  const int t  = threadIdx.x;
  const int lane = t & 63;
  const int wv = t >> 6;
  const int l15 = lane & 15, q = lane >> 4;
  if (t < 16){ sred[t] = 0.f; qred[t] = 0.f; }
  const int ntile = (wv == 0) ? 4 : 3;
  f32x4 acc[4];
  #pragma unroll
  for (int i = 0; i < 4; i++) acc[i] = (f32x4){0.f,0.f,0.f,0.f};
  for (int idx = t; idx < 256*RS/2; idx += 256) ((unsigned int*)img)[idx] = 0u;
  const long long inb = (long long)b*128*196;
  for (int ch = 0; ch < 2; ch++){
    __syncthreads();
    for (int idx = t; idx < 32*196; idx += 256){
      int c2 = idx / 196, px = idx % 196;
      int c = 2*c2;
      float f0 = in[inb + (long long)(ch*64 + c)*196 + px];
      float f1 = in[inb + (long long)(ch*64 + c + 1)*196 + px];
      int hp = (px/14 + 1)*16 + (px%14) + 1;
      *(unsigned int*)&img[hp*RS + c] = bf16r(f0) | (bf16r(f1) << 16);
    }
    __syncthreads();
    for (int ti = 0; ti < ntile; ti++){
      int tile = wv + ti*4;
      int px = tile*16 + l15;
      int pxe = px < 196 ? px : 195;
      int base = (pxe/14)*16 + (pxe%14);
      #pragma unroll
      for (int kk = 0; kk < 9; kk++){
        int hp = base + (kk/3)*16 + (kk%3);
        #pragma unroll
        for (int ks = 0; ks < 2; ks++){
          bf16x8 bfrag = *(const bf16x8*)&img[hp*RS + ks*32 + q*8];
          const unsigned short* wp = wb + (((long long)kk*128 + o0 + l15)*128 + ch*64 + ks*32 + q*8);
          bf16x8 afrag = *(const bf16x8*)wp;
          acc[ti] = __builtin_amdgcn_mfma_f32_16x16x32_bf16(afrag, bfrag, acc[ti], 0, 0, 0);
        }
      }
    }
  }
  float svl[4], qvl[4];
  #pragma unroll
  for (int r = 0; r < 4; r++){ svl[r] = 0.f; qvl[r] = 0.f; }
  for (int ti = 0; ti < ntile; ti++){
    int tile = wv + ti*4;
    int px = tile*16 + l15;
    if (px < 196){
      #pragma unroll
      for (int r = 0; r < 4; r++){
        int ol = q*4 + r;
        float v = acc[ti][r] + bias[o0 + ol];
        out[((long long)b*128 + o0 + ol)*196 + px] = v;
        svl[r] += v; qvl[r] += v*v;
      }
    }
  }
  #pragma unroll
  for (int r = 0; r < 4; r++){
    #pragma unroll
    for (int m = 1; m < 16; m <<= 1){
      svl[r] += __shfl_xor(svl[r], m);
      qvl[r] += __shfl_xor(qvl[r], m);
    }
  }
  if (l15 == 0){
    #pragma unroll
    for (int r = 0; r < 4; r++){
      atomicAdd(&sred[q*4 + r], svl[r]);
      atomicAdd(&qred[q*4 + r], qvl[r]);
    }
  }
  __syncthreads();
  if (t < 16){ atomicAdd(&sum[o0 + t], sred[t]); atomicAdd(&sq[o0 + t], qred[t]); }
}

// ---------------- tiled 3x3 conv, CS channels/barrier, 32-o tile, wT weights (convT3m) ----------------
template<int HIN,int WIN,int HOUT,int WOUT,int PAD,int CS>
__global__ __launch_bounds__(256)
void conv_tiled_w2(const float* __restrict__ in, const float* __restrict__ wT,
                   const float* __restrict__ bias, float* __restrict__ out,
                   float* __restrict__ sum, float* __restrict__ sq,
                   int Cin, int Cout, int act)
{
  constexpr int HP = HIN + 2*PAD, WP = WIN + 2*PAD, WPL = pad_stride(WP);
  constexpr int NR = WOUT + 2;
  __shared__ __align__(16) float img[CS][HP*WPL];
  __shared__ float wl[CS][32*9];
  const int b  = blockIdx.x;
  const int o0 = blockIdx.y * 32;
  const int t  = threadIdx.x;
  const int ol = t & 15, y = t >> 4;
  const bool act_th = (y < HOUT);
  float acc0[WOUT], acc1[WOUT];
  #pragma unroll
  for (int x = 0; x < WOUT; x++){ acc0[x] = 0.f; acc1[x] = 0.f; }
  for (int idx = t; idx < CS*HP*WPL; idx += 256) ((float*)img)[idx] = 0.f;
  const long long inb = (long long)b*Cin*HIN*WIN;
  const int CW9 = Cout*9;
  for (int c0 = 0; c0 < Cin; c0 += CS){
    __syncthreads();
    for (int idx = t; idx < CS*HIN*WIN; idx += 256){
      int cl = idx / (HIN*WIN), r = idx % (HIN*WIN);
      int iy = r / WIN, ix = r % WIN;
      img[cl][(iy+PAD)*WPL + (ix+PAD)] = in[inb + (long long)(c0+cl)*HIN*WIN + r];
    }
    for (int idx = t; idx < CS*288; idx += 256){
      int cl = idx / 288, r = idx % 288;
      wl[cl][r] = wT[(long long)(c0+cl)*CW9 + o0*9 + r];
    }
    __syncthreads();
    if (act_th){
      #pragma unroll
      for (int cl = 0; cl < CS; cl++){
        #pragma unroll
        for (int ky = 0; ky < 3; ky++){
          const float* row = &img[cl][(y+ky)*WPL];
          float rin[NR];
          #pragma unroll
          for (int q = 0; q < NR/4; q++){
            float4 v = ((const float4*)row)[q];
            rin[4*q+0]=v.x; rin[4*q+1]=v.y; rin[4*q+2]=v.z; rin[4*q+3]=v.w;
          }
          #pragma unroll
          for (int x = (NR/4)*4; x < NR; x++) rin[x] = row[x];
          #pragma unroll
          for (int kx = 0; kx < 3; kx++){
            float wv0 = wl[cl][ol*9 + ky*3 + kx];
            float wv1 = wl[cl][(ol+16)*9 + ky*3 + kx];
            #pragma unroll
            for (int x = 0; x < WOUT; x++){
              acc0[x] += wv0 * rin[x+kx];
              acc1[x] += wv1 * rin[x+kx];
            }
          }
        }
      }
    }
  }
  const int og0 = o0 + ol, og1 = o0 + ol + 16;
  float sv0 = 0.f, qv0 = 0.f, sv1 = 0.f, qv1 = 0.f;
  if (act_th){
    float bv0 = bias[og0], bv1 = bias[og1];
    float* po0 = out + (((long long)b*Cout + og0)*HOUT + y)*WOUT;
    float* po1 = out + (((long long)b*Cout + og1)*HOUT + y)*WOUT;
    #pragma unroll
    for (int x = 0; x < WOUT; x++){
      float v0 = acc0[x] + bv0;
      float v1 = acc1[x] + bv1;
      po0[x] = (act == 2) ? eluf(v0) : v0;
      po1[x] = (act == 2) ? eluf(v1) : v1;
      sv0 += v0; qv0 += v0*v0; sv1 += v1; qv1 += v1*v1;
    }
  }
  if (sum){
    sv0 += __shfl_down(sv0, 32); sv0 += __shfl_down(sv0, 16);
    qv0 += __shfl_down(qv0, 32); qv0 += __shfl_down(qv0, 16);
    sv1 += __shfl_down(sv1, 32); sv1 += __shfl_down(sv1, 16);
    qv1 += __shfl_down(qv1, 32); qv1 += __shfl_down(qv1, 16);
    if ((t & 63) < 16){
      atomicAdd(&sum[og0], sv0); atomicAdd(&sq[og0], qv0);
      atomicAdd(&sum[og1], sv1); atomicAdd(&sq[og1], qv1);
    }
  }
}

// ---------------- stride-2 transpose conv, parity-decomposed ----------------
template<int HIN,int WIN,int CIN,int COUT,bool DO_ELU>
__global__ __launch_bounds__(256)
void convt_s2_tiled(const float* __restrict__ in, const float* __restrict__ w,
                    const float* __restrict__ bias, float* __restrict__ out)
{
  constexpr int HOUT = 2*HIN - 1, WOUT = 2*WIN - 1;
  constexpr int RS = 20;
  __shared__ __align__(16) float img[17*RS];
  __shared__ float wl[16][10];
  const int b  = blockIdx.x;
  const int o0 = blockIdx.y * 16;
  const int t  = threadIdx.x;
  const int ol = t & 15, yb = t >> 4;
  for (int idx = t; idx < 17*RS; idx += 256) img[idx] = 0.f;
  float accA[WOUT], accB[WOUT];
  #pragma unroll
  for (int x = 0; x < WOUT; x++){ accA[x] = 0.f; accB[x] = 0.f; }
  for (int c = 0; c < CIN; c++){
    __syncthreads();
    for (int idx = t; idx < HIN*WIN; idx += 256)
      img[(idx/WIN)*RS + idx%WIN] = in[((long long)b*CIN + c)*HIN*WIN + idx];
    if (t < 144)
      wl[t/9][t%9] = w[(((long long)c*COUT + o0 + t/9)*3 + (t%9)/3)*3 + (t%9)%3];
    __syncthreads();
    float ru[16], rd[16];
    #pragma unroll
    for (int q = 0; q < 4; q++){
      float4 va = ((const float4*)&img[yb*RS])[q];
      ru[4*q+0]=va.x; ru[4*q+1]=va.y; ru[4*q+2]=va.z; ru[4*q+3]=va.w;
      float4 vb = ((const float4*)&img[(yb+1)*RS])[q];
      rd[4*q+0]=vb.x; rd[4*q+1]=vb.y; rd[4*q+2]=vb.z; rd[4*q+3]=vb.w;
    }
    float w00=wl[ol][0], w01=wl[ol][1], w02=wl[ol][2];
    float w10=wl[ol][3], w11=wl[ol][4], w12=wl[ol][5];
    float w20=wl[ol][6], w21=wl[ol][7], w22=wl[ol][8];
    #pragma unroll
    for (int v = 0; v < WIN; v++){
      accA[2*v] += w11*ru[v];
      accB[2*v] += w21*ru[v] + w01*rd[v];
    }
    #pragma unroll
    for (int v = 0; v < WIN-1; v++){
      accA[2*v+1] += w12*ru[v] + w10*ru[v+1];
      accB[2*v+1] += w22*ru[v] + w20*ru[v+1] + w02*rd[v] + w00*rd[v+1];
    }
  }
  const int og = o0 + ol;
  const float bv = bias[og];
  const int yA = 2*yb, yB = 2*yb + 1;
  if (yA < HOUT){
    float* po = out + (((long long)b*COUT + og)*HOUT + yA)*WOUT;
    #pragma unroll
    for (int x = 0; x < WOUT; x++){ float v = accA[x] + bv; po[x] = DO_ELU ? eluf(v) : v; }
  }
  if (yB < HOUT){
    float* po = out + (((long long)b*COUT + og)*HOUT + yB)*WOUT;
    #pragma unroll
    for (int x = 0; x < WOUT; x++){ float v = accB[x] + bv; po[x] = DO_ELU ? eluf(v) : v; }
  }
}

// ---------------- deform weight transpose: w[o][c][kk] -> fp32 wT[cc][cl*9+kk][o] ----------------
__global__ void wtrans_kernel(const float* __restrict__ w, float* __restrict__ wT,
                              int CIN, int COUT)
{
  int n = CIN*COUT*9;
  int idx = blockIdx.x*256 + threadIdx.x;
  if (idx >= n) return;
  int cc = idx / (72*COUT);
  int r  = idx % (72*COUT);
  int k  = r / COUT, o = r % COUT;
  int c  = cc*8 + k/9, kk = k%9;
  wT[idx] = w[((long long)o*CIN + c)*9 + kk];
}

// ---------------- deformable conv: gather + register-tiled GEMM, packed idx, optional fp32 LDS wstage ----------------
template<int CIN,int COUT,int H,int W,int PXT,int OG,int PG,int COB,bool WSTAGE>
__global__ __launch_bounds__(256)
void deform_gemm(const float* __restrict__ x, const float* __restrict__ om,
                 const float* __restrict__ wT, float* __restrict__ out,
                 float* __restrict__ sum, float* __restrict__ sq)
{
  constexpr int HW = H*W;
  constexpr int NT = (HW + PXT - 1)/PXT;
  constexpr int PXTP = 64;
  constexpr int OT = COB/OG;
  constexpr int PT = PXTP/PG;
  __shared__ __align__(16) float simg[8*HW];
  __shared__ __align__(16) float S[72*PXTP];
  __shared__ __align__(16) float wlds[WSTAGE ? 72*COB : 1];
  __shared__ float kwv[PXT*9*4];
  __shared__ unsigned int kidx[PXT*9];
  __shared__ float sred[COB], qred[COB];
  const int tile = blockIdx.x % NT;
  const int b    = blockIdx.x / NT;
  const int obase = blockIdx.y * COB;
  const int t    = threadIdx.x;
  const int og   = t % OG;
  const int pxg  = t / OG;
  const int Hp = H + 2, Wp = W + 2;
  if (t < COB){ sred[t] = 0.f; qred[t] = 0.f; }
  // phase 0: bilinear corner weights + packed u8x4 indices
  for (int it = t; it < PXT*9; it += 256){
    int px = it / 9, kk = it % 9;
    int p = tile*PXT + px;
    float w0=0.f,w1=0.f,w2=0.f,w3=0.f;
    unsigned int i0=0,i1=0,i2=0,i3=0;
    if (p < HW){
      int i = p / W, j = p % W;
      long long base = ((long long)b*27)*HW + p;
      float offx = om[base + (long long)kk*HW];
      float offy = om[base + (long long)(9+kk)*HW];
      float mk   = om[base + (long long)(18+kk)*HW];
      float pnx = (float)(kk/3) - 1.f;
      float pny = (float)(kk%3) - 1.f;
      float px_ = fminf(fmaxf((float)(i+1) + pnx + offx, 0.f), (float)(Hp-1));
      float py_ = fminf(fmaxf((float)(j+1) + pny + offy, 0.f), (float)(Wp-1));
      float fx = floorf(px_), fy = floorf(py_);
      float x0 = fmaxf(fx, 0.f), y0 = fmaxf(fy, 0.f);
      float x1c = fminf(fx + 1.f, (float)(Hp-1));
      float y1c = fminf(fy + 1.f, (float)(Wp-1));
      float glt = (1.f + (x0 - px_)) * (1.f + (y0 - py_));
      float grb = (1.f - (x1c - px_)) * (1.f - (y1c - py_));
      float glb = (1.f + (x0 - px_)) * (1.f - (y1c - py_));
      float grt = (1.f - (x1c - px_)) * (1.f + (y0 - py_));
      int ax0=(int)x0, ay0=(int)y0, ax1=(int)x1c, ay1=(int)y1c;
      if (ax0>=1 && ax0<=H && ay0>=1 && ay0<=W){ w0 = glt*mk; i0 = (ax0-1)*W + (ay0-1); }
      if (ax1>=1 && ax1<=H && ay1>=1 && ay1<=W){ w1 = grb*mk; i1 = (ax1-1)*W + (ay1-1); }
      if (ax0>=1 && ax0<=H && ay1>=1 && ay1<=W){ w2 = glb*mk; i2 = (ax0-1)*W + (ay1-1); }
      if (ax1>=1 && ax1<=H && ay0>=1 && ay0<=W){ w3 = grt*mk; i3 = (ax1-1)*W + (ay0-1); }
    }
    int b4 = it*4;
    kwv[b4+0]=w0; kwv[b4+1]=w1; kwv[b4+2]=w2; kwv[b4+3]=w3;
    kidx[it] = i0 | (i1 << 8) | (i2 << 16) | (i3 << 24);
  }
  float acc[OT][PT];
  #pragma unroll
  for (int oi = 0; oi < OT; oi++)
    #pragma unroll
    for (int pp = 0; pp < PT; pp++) acc[oi][pp] = 0.f;
  for (int cc = 0; cc < CIN/8; cc++){
    __syncthreads();
    for (int idx = t; idx < 8*HW; idx += 256)
      simg[idx] = x[((long long)b*CIN + cc*8)*HW + idx];
    if (WSTAGE){
      for (int idx = t; idx < 72*COB; idx += 256){
        int k = idx / COB, oo = idx % COB;
        wlds[idx] = wT[(long long)cc*72*COUT + k*COUT + obase + oo];
      }
    }
    __syncthreads();
    for (int idx = t; idx < 72*PXTP; idx += 256){
      int k = idx >> 6, px = idx & 63;
      float v = 0.f;
      if (px < PXT){
        int it = px*9 + (k%9);
        int b4 = it*4;
        unsigned int pk = kidx[it];
        const float* im = &simg[(k/9)*HW];
        v = kwv[b4+0]*im[pk & 255] + kwv[b4+1]*im[(pk >> 8) & 255]
          + kwv[b4+2]*im[(pk >> 16) & 255] + kwv[b4+3]*im[pk >> 24];
      }
      S[idx] = v;
    }
    __syncthreads();
    const float* wc = wT + (long long)cc*72*COUT;
    #pragma unroll 8
    for (int k = 0; k < 72; k++){
      float wreg[OT];
      #pragma unroll
      for (int ow = 0; ow < OT/4; ow++){
        float4 wv;
        if (WSTAGE) wv = *(const float4*)(&wlds[k*COB + og*OT + ow*4]);
        else        wv = *(const float4*)(wc + k*COUT + obase + og*OT + ow*4);
        wreg[ow*4+0]=wv.x; wreg[ow*4+1]=wv.y; wreg[ow*4+2]=wv.z; wreg[ow*4+3]=wv.w;
      }
      if constexpr (PT % 4 == 0){
        #pragma unroll
        for (int pq = 0; pq < PT/4; pq++){
          const float4 s4 = *(const float4*)(&S[k*PXTP + pxg*PT + pq*4]);
          #pragma unroll
          for (int oi = 0; oi < OT; oi++){
            acc[oi][pq*4+0] += wreg[oi]*s4.x;
            acc[oi][pq*4+1] += wreg[oi]*s4.y;
            acc[oi][pq*4+2] += wreg[oi]*s4.z;
            acc[oi][pq*4+3] += wreg[oi]*s4.w;
          }
        }
      } else {
        const float2 s2 = *(const float2*)(&S[k*PXTP + pxg*PT]);
        #pragma unroll
        for (int oi = 0; oi < OT; oi++){
          acc[oi][0] += wreg[oi]*s2.x;
          acc[oi][1] += wreg[oi]*s2.y;
        }
      }
    }
  }
  float svl[OT], qvl[OT];
  #pragma unroll
  for (int oi = 0; oi < OT; oi++){ svl[oi] = 0.f; qvl[oi] = 0.f; }
  #pragma unroll
  for (int oi = 0; oi < OT; oi++){
    int o = obase + og*OT + oi;
    #pragma unroll
    for (int pp = 0; pp < PT; pp++){
      int pxl = pxg*PT + pp;
      if (pxl < PXT){
        int p = tile*PXT + pxl;
        if (p < HW){
          float v = acc[oi][pp];
          out[((long long)b*COUT + o)*HW + p] = v;
          svl[oi] += v; qvl[oi] += v*v;
        }
      }
    }
  }
  #pragma unroll
  for (int oi = 0; oi < OT; oi++){
    atomicAdd(&sred[og*OT + oi], svl[oi]);
    atomicAdd(&qred[og*OT + oi], qvl[oi]);
  }
  __syncthreads();
  if (t < COB){ atomicAdd(&sum[obase + t], sred[t]); atomicAdd(&sq[obase + t], qred[t]); }
}

// ---------------- bn + elu + 2x2 avgpool ----------------
__global__ void bn_elu_pool_kernel(const float* __restrict__ in, const float* __restrict__ g,
                                   const float* __restrict__ bb, const float* __restrict__ sum,
                                   const float* __restrict__ sq, float* __restrict__ out,
                                   int B, int C, int H, int W, float invN)
{
  int Ho = H/2, Wo = W/2;
  int idx = blockIdx.x*256 + threadIdx.x;
  int total = B*C*Ho*Wo;
  if (idx >= total) return;
  int x = idx % Wo; int t = idx / Wo;
  int y = t % Ho;   t /= Ho;
  int c = t % C;    int b = t / C;
  float mean = sum[c]*invN;
  float var  = sq[c]*invN - mean*mean;
  float sc = g[c] * rsqrtf(var + 1e-5f);
  float sh = bb[c] - mean*sc;
  const float* p = in + (long long)(b*C + c)*H*W;
  float acc = 0.f;
  #pragma unroll
  for (int dy = 0; dy < 2; dy++)
    #pragma unroll
    for (int dx = 0; dx < 2; dx++)
      acc += eluf(sc*p[(2*y+dy)*W + (2*x+dx)] + sh);
  out[idx] = acc * 0.25f;
}

// ---------------- bn + elu in place ----------------
__global__ void bn_elu_inplace_kernel(float* __restrict__ xio, const float* __restrict__ g,
                                      const float* __restrict__ bb, const float* __restrict__ sum,
                                      const float* __restrict__ sq, int C, int HW, float invN, int total)
{
  int idx = blockIdx.x*256 + threadIdx.x;
  if (idx >= total) return;
  int c = (idx / HW) % C;
  float mean = sum[c]*invN;
  float var  = sq[c]*invN - mean*mean;
  float sc = g[c] * rsqrtf(var + 1e-5f);
  float sh = bb[c] - mean*sc;
  xio[idx] = eluf(sc*xio[idx] + sh);
}

// ---------------- generic transpose conv (kept for convT1m) ----------------
__global__ void convt_kernel(const float* __restrict__ in, const float* __restrict__ w,
                             const float* __restrict__ bias, float* __restrict__ out,
                             int B, int Cin, int Cout, int Hin, int Win, int Hout, int Wout,
                             int K, int S, int PP, int do_elu)
{
  int idx = blockIdx.x*256 + threadIdx.x;
  int total = B*Cout*Hout*Wout;
  if (idx >= total) return;
  int x = idx % Wout; int t = idx / Wout;
  int y = t % Hout;   t /= Hout;
  int o = t % Cout;   int b = t / Cout;
  float acc = bias[o];
  for (int ky = 0; ky < K; ky++){
    int dy = y + ky - PP;
    if (dy < 0 || (dy % S) != 0) continue;
    int iy = dy / S; if (iy >= Hin) continue;
    int wky = K - 1 - ky;
    for (int kx = 0; kx < K; kx++){
      int dx = x + kx - PP;
      if (dx < 0 || (dx % S) != 0) continue;
      int ix = dx / S; if (ix >= Win) continue;
      int wkx = K - 1 - kx;
      const float* ip = in + (long long)b*Cin*Hin*Win + (long long)iy*Win + ix;
      for (int c = 0; c < Cin; c++){
        acc += w[(((long long)c*Cout + o)*K + wky)*K + wkx] * ip[(long long)c*Hin*Win];
      }
    }
  }
  if (do_elu) acc = eluf(acc);
  out[idx] = acc;
}

// ---------------- final bicubic warp ----------------
__device__ __forceinline__ float cubicf(float A, float Bv, float C, float D, float t){
  float a = -0.5f*A + 1.5f*Bv - 1.5f*C + 0.5f*D;
  float b =  A - 2.5f*Bv + 2.0f*C - 0.5f*D;
  float c = -0.5f*A + 0.5f*C;
  return ((a*t + b)*t + c)*t + Bv;
}

__global__ void warp_kernel(const float* __restrict__ V, const float* __restrict__ x1,
                            float* __restrict__ out, int B)
{
  int idx = blockIdx.x*256 + threadIdx.x;
  int total = B*784;
  if (idx >= total) return;
  int j = idx % 28; int t = idx / 28;
  int i = t % 28;   int b = t / 28;
  float v0 = V[((long long)b*2 + 0)*784 + j*28 + i];
  float v1 = V[((long long)b*2 + 1)*784 + j*28 + i];
  float gx = (-1.f + 2.f*(float)j/27.f) + v0;
  float gy = (-1.f + 2.f*(float)i/27.f) + v1;
  float ix = (gx + 1.f)*13.5f;
  float iy = (gy + 1.f)*13.5f;
  float x0 = floorf(ix), y0 = floorf(iy);
  float tx = ix - x0, ty = iy - y0;
  const float* img = x1 + (long long)b*2*784;
  float rows[4];
  #pragma unroll
  for (int ky = -1; ky <= 2; ky++){
    int yi = (int)fminf(fmaxf(y0 + (float)ky, 0.f), 27.f);
    float cv[4];
    #pragma unroll
    for (int kx = -1; kx <= 2; kx++){
      int xi = (int)fminf(fmaxf(x0 + (float)kx, 0.f), 27.f);
      cv[kx+1] = img[yi*28 + xi];
    }
    rows[ky+1] = cubicf(cv[0], cv[1], cv[2], cv[3], tx);
  }
  out[idx] = cubicf(rows[0], rows[1], rows[2], rows[3], ty);
}

// ---------------- host ----------------
extern "C" void kernel_launch(void* const* d_in, const int* in_sizes, int n_in,
                              void* d_out, int out_size, void* d_ws, size_t ws_size,
                              hipStream_t stream)
{
  const int B = 256;
  const float* x1      = (const float*)d_in[0];
  const float* conv1_w = (const float*)d_in[9];
  const float* conv1_b = (const float*)d_in[10];
  const float* bn1_g   = (const float*)d_in[11];
  const float* bn1_b   = (const float*)d_in[12];
  const float* dc2_pw  = (const float*)d_in[13];
  const float* dc2_pb  = (const float*)d_in[14];
  const float* dc2_mw  = (const float*)d_in[15];
  const float* dc2_mb  = (const float*)d_in[16];
  const float* dc2_w   = (const float*)d_in[17];
  const float* bn2_g   = (const float*)d_in[18];
  const float* bn2_b   = (const float*)d_in[19];
  const float* conv3_w = (const float*)d_in[20];
  const float* conv3_b = (const float*)d_in[21];
  const float* bn3_g   = (const float*)d_in[22];
  const float* bn3_b   = (const float*)d_in[23];
  const float* dc41_pw = (const float*)d_in[24];
  const float* dc41_pb = (const float*)d_in[25];
  const float* dc41_mw = (const float*)d_in[26];
  const float* dc41_mb = (const float*)d_in[27];
  const float* dc41_w  = (const float*)d_in[28];
  const float* bn41_g  = (const float*)d_in[29];
  const float* bn41_b  = (const float*)d_in[30];
  const float* conv4_w = (const float*)d_in[31];
  const float* conv4_b = (const float*)d_in[32];
  const float* conv4m_w= (const float*)d_in[33];
  const float* conv4m_b= (const float*)d_in[34];
  const float* conv3m_w= (const float*)d_in[35];
  const float* conv3m_b= (const float*)d_in[36];
  const float* conv2m_w= (const float*)d_in[37];
  const float* conv2m_b= (const float*)d_in[38];
  const float* conv1m_w= (const float*)d_in[39];
  const float* conv1m_b= (const float*)d_in[40];

  float* ws = (float*)d_ws;

  // lifetime-packed arena (floats), stats in [0,1024). (R15-R17 layout — verified)
  const long long AB = 1024;
  float* p1   = ws + AB;
  float* a1   = ws + AB + 3211264;
  float* om2  = ws + AB + 3211264;
  float* a2   = ws + AB + 4566016;
  float* a3   = ws + AB + 10988544;
  float* p2   = ws + AB;
  float* om41 = ws + AB + 1605632;
  float* a41  = ws + AB + 1944320;
  float* a4   = ws + AB + 2747136;
  float* t4m  = ws + AB + 2772224;
  float* t3m  = ws + AB + 8310016;
  float* t2m  = ws + AB + 11996416;
  float* t1m  = ws + AB;
  float* wT2  = ws + AB + 17411072;
  float* wT41 = ws + AB + 17484800;
  float* wT3m = ws + AB + 17705984;
  unsigned short* wb3 = (unsigned short*)(ws + AB + 17779712);

  float* s1  = ws + 0;   float* q1  = ws + 64;
  float* s2  = ws + 128; float* q2  = ws + 256;
  float* s3  = ws + 384; float* q3  = ws + 512;
  float* s41 = ws + 640; float* q41 = ws + 704;

  auto nb = [](long long n){ return (int)((n + 255)/256); };

  hipMemsetAsync(d_ws, 0, 4096, stream);

  // weight pre-transposes / packs
  wtrans_kernel<<<nb(73728), 256, 0, stream>>>(dc2_w,  wT2,  64, 128);
  wtrans_kernel<<<nb(73728), 256, 0, stream>>>(dc41_w, wT41, 128, 64);
  wtrans3_kernel<<<nb(73728), 256, 0, stream>>>(conv3m_w, wT3m, 128, 64, 1);
  wconv3_bf16_kernel<<<nb(147456), 256, 0, stream>>>(conv3_w, wb3);

  // [1] conv1 (2->64, 28x28), fused bn1 stats
  conv1_tiled<<<dim3(B,8), 256, 0, stream>>>(x1, conv1_w, conv1_b, a1, s1, q1);
  // [2] bn1 + elu + avgpool -> p1
  bn_elu_pool_kernel<<<nb((long long)B*64*196), 256, 0, stream>>>(a1, bn1_g, bn1_b, s1, q1, p1,
                                                                  B, 64, 28, 28, 1.f/200704.f);
  // [3] dc2 offsets (64->18) + mask (64->9, sigmoid) -> om2
  conv_tiled<14,14,14,14,1><<<dim3(B,2), 256, 0, stream>>>(p1, dc2_pw, dc2_pb, om2,
                                                           64, 18, 27, 0, 0);
  conv_tiled<14,14,14,14,1><<<dim3(B,1), 256, 0, stream>>>(p1, dc2_mw, dc2_mb, om2,
                                                           64, 9, 27, 18, 1);
  // [4] deform conv 2 (64->128) -> a2, fused bn2 stats; 4o x 8px, packed idx, deep unroll
  deform_gemm<64,128,14,14,49,32,8,128,false><<<dim3(B*4,1), 256, 0, stream>>>(p1, om2, wT2, a2, s2, q2);
  // [5] bn2 + elu
  bn_elu_inplace_kernel<<<nb((long long)B*128*196), 256, 0, stream>>>(a2, bn2_g, bn2_b, s2, q2,
                                                                      128, 196, 1.f/50176.f, B*128*196);
  // [6] conv3 (128->128) -> a3 via bf16 MFMA, fused bn3 stats
  conv3_mfma<<<dim3(B,8), 256, 0, stream>>>(a2, wb3, conv3_b, a3, s3, q3);
  // [7] bn3 + elu + avgpool -> p2
  bn_elu_pool_kernel<<<nb((long long)B*128*49), 256, 0, stream>>>(a3, bn3_g, bn3_b, s3, q3, p2,
                                                                  B, 128, 14, 14, 1.f/50176.f);
  // [8] dc41 offsets + mask -> om41
  conv_tiled<7,7,7,7,1><<<dim3(B,2), 256, 0, stream>>>(p2, dc41_pw, dc41_pb, om41,
                                                       128, 18, 27, 0, 0);
  conv_tiled<7,7,7,7,1><<<dim3(B,1), 256, 0, stream>>>(p2, dc41_mw, dc41_mb, om41,
                                                       128, 9, 27, 18, 1);
  // [9] deform conv 41 (128->64) -> a41, fused bn41 stats; o-split x2 + fp32 LDS weight stage
  deform_gemm<128,64,7,7,49,8,32,32,true><<<dim3(B,2), 256, 0, stream>>>(p2, om41, wT41, a41, s41, q41);
  // [10] bn41 + elu
  bn_elu_inplace_kernel<<<nb((long long)B*64*49), 256, 0, stream>>>(a41, bn41_g, bn41_b, s41, q41,
                                                                    64, 49, 1.f/12544.f, B*64*49);
  // [11] conv4 (64->2, 7x7) naive (tiny)
  conv3x3_kernel<<<nb((long long)B*2*49), 256, 0, stream>>>(a41, conv4_w, conv4_b, a4,
                                                            B, 64, 2, 7, 7, 2, 0, 0);
  // [12] convT4m: 2->128, s=2, p=1, 7->13, parity-decomposed
  convt_s2_tiled<7,7,2,128,false><<<dim3(B,8), 256, 0, stream>>>(a4, conv4m_w, conv4m_b, t4m);
  // [13] convT3m: 128->64, s=1 == conv pad2 flipped (pre-transposed), 32-o tile, CS=2, +elu
  conv_tiled_w2<13,13,15,15,2,2><<<dim3(B,2), 256, 0, stream>>>(t4m, wT3m, conv3m_b, t3m,
                                                                nullptr, nullptr, 128, 64, 2);
  // [14] convT2m: 64->32, s=2, p=1, 15->29, +elu, parity-decomposed
  convt_s2_tiled<15,15,64,32,true><<<dim3(B,2), 256, 0, stream>>>(t3m, conv2m_w, conv2m_b, t2m);
  // [15] convT1m: 32->2, k=2, s=1, p=1, 29->28, +elu (naive, tiny)
  convt_kernel<<<nb((long long)B*2*784), 256, 0, stream>>>(t2m, conv1m_w, conv1m_b, t1m,
                                                           B, 32, 2, 29, 29, 28, 28, 2, 1, 0, 1);
  // [16] final warp
  warp_kernel<<<nb((long long)B*784), 256, 0, stream>>>(t1m, x1, (float*)d_out, B);
}

// Round 22
// 1320.385 us; speedup vs baseline: 1.0509x; 1.0509x over previous
//
#include <hip/hip_runtime.h>
#include <hip/hip_bf16.h>

__device__ __forceinline__ float eluf(float x){ return x > 0.f ? x : expm1f(x); }

typedef __attribute__((ext_vector_type(8))) short bf16x8;
typedef __attribute__((ext_vector_type(4))) float f32x4;

__device__ __forceinline__ unsigned int bf16r(float f){
  unsigned int u = __float_as_uint(f);
  return (u + 0x7FFFu + ((u >> 16) & 1u)) >> 16;   // RNE
}

// LDS row stride helper
constexpr int pad_stride(int wp){
  int s = (wp + 3) & ~3;
  return (s % 8 == 0) ? s + 4 : s;
}

// ---------------- naive 3x3 pad-1 conv (kept only for tiny conv4) ----------------
__global__ void conv3x3_kernel(const float* __restrict__ in, const float* __restrict__ w,
                               const float* __restrict__ bias, float* __restrict__ out,
                               int B, int Cin, int Cout, int H, int W, int Ctot, int ooff, int act)
{
  int idx = blockIdx.x*256 + threadIdx.x;
  int total = B*Cout*H*W;
  if (idx >= total) return;
  int x = idx % W; int t = idx / W;
  int y = t % H;   t /= H;
  int o = t % Cout; int b = t / Cout;
  float acc = bias ? bias[o] : 0.f;
  const float* wp = w + (long long)o*Cin*9;
  for (int c = 0; c < Cin; c++){
    const float* ip = in + (long long)(b*Cin + c)*H*W;
    const float* wc = wp + c*9;
    #pragma unroll
    for (int ky = 0; ky < 3; ky++){
      int iy = y + ky - 1; if ((unsigned)iy >= (unsigned)H) continue;
      #pragma unroll
      for (int kx = 0; kx < 3; kx++){
        int ix = x + kx - 1; if ((unsigned)ix >= (unsigned)W) continue;
        acc += wc[ky*3+kx] * ip[iy*W + ix];
      }
    }
  }
  if (act == 1) acc = 1.f/(1.f + expf(-acc));
  out[(((long long)b*Ctot + ooff + o)*H + y)*W + x] = acc;
}

// ---------------- conv1: 2->64, 28x28, fused bn-stats ----------------
__global__ __launch_bounds__(256)
void conv1_tiled(const float* __restrict__ in, const float* __restrict__ w,
                 const float* __restrict__ bias, float* __restrict__ out,
                 float* __restrict__ sum, float* __restrict__ sq)
{
  constexpr int WPL = pad_stride(30);   // 36
  __shared__ __align__(16) float img[2][30*WPL];
  __shared__ float wl[2][8*9];
  const int b = blockIdx.x, o0 = blockIdx.y*8, t = threadIdx.x;
  const int ol = t & 7, y = t >> 3;
  for (int idx = t; idx < 2*30*WPL; idx += 256) ((float*)img)[idx] = 0.f;
  __syncthreads();
  for (int idx = t; idx < 2*784; idx += 256){
    int cl = idx/784, r = idx%784;
    img[cl][(r/28 + 1)*WPL + (r%28) + 1] = in[((long long)b*2)*784 + idx];
  }
  if (t < 144){
    int cl = t/72, r = t%72;
    wl[cl][r] = w[(((long long)(o0 + r/9))*2 + cl)*9 + (r%9)];
  }
  __syncthreads();
  const bool active = (y < 28);
  float acc[28];
  #pragma unroll
  for (int x = 0; x < 28; x++) acc[x] = 0.f;
  if (active){
    for (int cl = 0; cl < 2; cl++){
      #pragma unroll
      for (int ky = 0; ky < 3; ky++){
        const float* row = &img[cl][(y+ky)*WPL];
        float rin[30];
        #pragma unroll
        for (int q = 0; q < 7; q++){
          float4 v = ((const float4*)row)[q];
          rin[4*q+0]=v.x; rin[4*q+1]=v.y; rin[4*q+2]=v.z; rin[4*q+3]=v.w;
        }
        rin[28] = row[28]; rin[29] = row[29];
        #pragma unroll
        for (int kx = 0; kx < 3; kx++){
          float wv = wl[cl][ol*9 + ky*3 + kx];
          #pragma unroll
          for (int x = 0; x < 28; x++) acc[x] += wv * rin[x+kx];
        }
      }
    }
  }
  const int og = o0 + ol;
  float sv = 0.f, qv = 0.f;
  if (active){
    float bv = bias[og];
    float* po = out + (((long long)b*64 + og)*28 + y)*28;
    #pragma unroll
    for (int x = 0; x < 28; x++){
      float v = acc[x] + bv;
      po[x] = v;
      sv += v; qv += v*v;
    }
  }
  #pragma unroll
  for (int d = 32; d >= 8; d >>= 1){
    sv += __shfl_down(sv, d);
    qv += __shfl_down(qv, d);
  }
  if ((t & 63) < 8){ atomicAdd(&sum[og], sv); atomicAdd(&sq[og], qv); }
}

// ---------------- tiled 3x3 conv, CS=1, 16-o tile (for small Cout convs) ----------------
template<int HIN,int WIN,int HOUT,int WOUT,int PAD>
__global__ __launch_bounds__(256)
void conv_tiled(const float* __restrict__ in, const float* __restrict__ w,
                const float* __restrict__ bias, float* __restrict__ out,
                int Cin, int Cout, int Ctot, int ooff, int act)
{
  constexpr int HP = HIN + 2*PAD, WP = WIN + 2*PAD, WPL = pad_stride(WP);
  constexpr int NR = WOUT + 2;
  __shared__ __align__(16) float img[HP*WPL];
  __shared__ float wl[16*9];
  const int b  = blockIdx.x;
  const int o0 = blockIdx.y * 16;
  const int t  = threadIdx.x;
  const int ol = t & 15, y = t >> 4;
  const bool act_th = (y < HOUT) && (o0 + ol < Cout);
  float acc[WOUT];
  #pragma unroll
  for (int x = 0; x < WOUT; x++) acc[x] = 0.f;
  for (int idx = t; idx < HP*WPL; idx += 256) img[idx] = 0.f;
  const long long inb = (long long)b*Cin*HIN*WIN;
  for (int c = 0; c < Cin; c++){
    __syncthreads();
    for (int idx = t; idx < HIN*WIN; idx += 256){
      int iy = idx / WIN, ix = idx % WIN;
      img[(iy+PAD)*WPL + (ix+PAD)] = in[inb + (long long)c*HIN*WIN + idx];
    }
    if (t < 144){
      int oo = t / 9, kk = t % 9;
      int og = o0 + oo;
      wl[t] = (og < Cout) ? w[((long long)og*Cin + c)*9 + kk] : 0.f;
    }
    __syncthreads();
    if (act_th){
      #pragma unroll
      for (int ky = 0; ky < 3; ky++){
        const float* row = &img[(y+ky)*WPL];
        float rin[NR];
        #pragma unroll
        for (int q = 0; q < NR/4; q++){
          float4 v = ((const float4*)row)[q];
          rin[4*q+0]=v.x; rin[4*q+1]=v.y; rin[4*q+2]=v.z; rin[4*q+3]=v.w;
        }
        #pragma unroll
        for (int x = (NR/4)*4; x < NR; x++) rin[x] = row[x];
        #pragma unroll
        for (int kx = 0; kx < 3; kx++){
          float wv = wl[ol*9 + ky*3 + kx];
          #pragma unroll
          for (int x = 0; x < WOUT; x++) acc[x] += wv * rin[x+kx];
        }
      }
    }
  }
  if (act_th){
    int og = o0 + ol;
    float bv = bias[og];
    #pragma unroll
    for (int x = 0; x < WOUT; x++){
      float v = acc[x] + bv;
      if (act == 1) v = 1.f/(1.f + expf(-v));
      else if (act == 2) v = eluf(v);
      out[(((long long)b*Ctot + ooff + og)*HOUT + y)*WOUT + x] = v;
    }
  }
}

// ---------------- conv weight transpose: -> wT[c][o*9+kk] (flip for transpose-conv) ----------------
__global__ void wtrans3_kernel(const float* __restrict__ w, float* __restrict__ wT,
                               int Cin, int Cout, int flip)
{
  int n = Cin*Cout*9;
  int idx = blockIdx.x*256 + threadIdx.x;
  if (idx >= n) return;
  int c  = idx / (Cout*9);
  int r  = idx % (Cout*9);
  int o  = r / 9, kk = r % 9;
  float v;
  if (flip) v = w[((long long)c*Cout + o)*9 + (2 - kk/3)*3 + (2 - kk%3)];
  else      v = w[((long long)o*Cin + c)*9 + kk];
  wT[idx] = v;
}

// ---------------- conv3 weights -> bf16 wb[kk][o][c] ----------------
__global__ void wconv3_bf16_kernel(const float* __restrict__ w, unsigned short* __restrict__ wb)
{
  int idx = blockIdx.x*256 + threadIdx.x;
  if (idx >= 147456) return;
  int kk = idx >> 14;
  int r  = idx & 16383;
  int o  = r >> 7, c = r & 127;
  wb[idx] = (unsigned short)bf16r(w[((long long)o*128 + c)*9 + kk]);
}

// ---------------- conv3 via bf16 MFMA (shift-decomposed implicit GEMM) ----------------
__global__ __launch_bounds__(256)
void conv3_mfma(const float* __restrict__ in, const unsigned short* __restrict__ wb,
                const float* __restrict__ bias, float* __restrict__ out,
                float* __restrict__ sum, float* __restrict__ sq)
{
  constexpr int RS = 88;                   // u16 per hp row (64 ch + 24 pad) = 176 B
  __shared__ unsigned short img[256*RS];
  __shared__ float sred[16], qred[16];
  const int b  = blockIdx.x;
  const int o0 = blockIdx.y * 16;
  const int t  = threadIdx.x;
  const int lane = t & 63;
  const int wv = t >> 6;
  const int l15 = lane & 15, q = lane >> 4;
  if (t < 16){ sred[t] = 0.f; qred[t] = 0.f; }
  const int ntile = (wv == 0) ? 4 : 3;
  f32x4 acc[4];
  #pragma unroll
  for (int i = 0; i < 4; i++) acc[i] = (f32x4){0.f,0.f,0.f,0.f};
  for (int idx = t; idx < 256*RS/2; idx += 256) ((unsigned int*)img)[idx] = 0u;
  const long long inb = (long long)b*128*196;
  for (int ch = 0; ch < 2; ch++){
    __syncthreads();
    for (int idx = t; idx < 32*196; idx += 256){
      int c2 = idx / 196, px = idx % 196;
      int c = 2*c2;
      float f0 = in[inb + (long long)(ch*64 + c)*196 + px];
      float f1 = in[inb + (long long)(ch*64 + c + 1)*196 + px];
      int hp = (px/14 + 1)*16 + (px%14) + 1;
      *(unsigned int*)&img[hp*RS + c] = bf16r(f0) | (bf16r(f1) << 16);
    }
    __syncthreads();
    for (int ti = 0; ti < ntile; ti++){
      int tile = wv + ti*4;
      int px = tile*16 + l15;
      int pxe = px < 196 ? px : 195;
      int base = (pxe/14)*16 + (pxe%14);
      #pragma unroll
      for (int kk = 0; kk < 9; kk++){
        int hp = base + (kk/3)*16 + (kk%3);
        #pragma unroll
        for (int ks = 0; ks < 2; ks++){
          bf16x8 bfrag = *(const bf16x8*)&img[hp*RS + ks*32 + q*8];
          const unsigned short* wp = wb + (((long long)kk*128 + o0 + l15)*128 + ch*64 + ks*32 + q*8);
          bf16x8 afrag = *(const bf16x8*)wp;
          acc[ti] = __builtin_amdgcn_mfma_f32_16x16x32_bf16(afrag, bfrag, acc[ti], 0, 0, 0);
        }
      }
    }
  }
  float svl[4], qvl[4];
  #pragma unroll
  for (int r = 0; r < 4; r++){ svl[r] = 0.f; qvl[r] = 0.f; }
  for (int ti = 0; ti < ntile; ti++){
    int tile = wv + ti*4;
    int px = tile*16 + l15;
    if (px < 196){
      #pragma unroll
      for (int r = 0; r < 4; r++){
        int ol = q*4 + r;
        float v = acc[ti][r] + bias[o0 + ol];
        out[((long long)b*128 + o0 + ol)*196 + px] = v;
        svl[r] += v; qvl[r] += v*v;
      }
    }
  }
  #pragma unroll
  for (int r = 0; r < 4; r++){
    #pragma unroll
    for (int m = 1; m < 16; m <<= 1){
      svl[r] += __shfl_xor(svl[r], m);
      qvl[r] += __shfl_xor(qvl[r], m);
    }
  }
  if (l15 == 0){
    #pragma unroll
    for (int r = 0; r < 4; r++){
      atomicAdd(&sred[q*4 + r], svl[r]);
      atomicAdd(&qred[q*4 + r], qvl[r]);
    }
  }
  __syncthreads();
  if (t < 16){ atomicAdd(&sum[o0 + t], sred[t]); atomicAdd(&sq[o0 + t], qred[t]); }
}

// ---------------- tiled 3x3 conv, CS channels/barrier, 32-o tile, wT weights (convT3m) ----------------
template<int HIN,int WIN,int HOUT,int WOUT,int PAD,int CS>
__global__ __launch_bounds__(256)
void conv_tiled_w2(const float* __restrict__ in, const float* __restrict__ wT,
                   const float* __restrict__ bias, float* __restrict__ out,
                   float* __restrict__ sum, float* __restrict__ sq,
                   int Cin, int Cout, int act)
{
  constexpr int HP = HIN + 2*PAD, WP = WIN + 2*PAD, WPL = pad_stride(WP);
  constexpr int NR = WOUT + 2;
  __shared__ __align__(16) float img[CS][HP*WPL];
  __shared__ float wl[CS][32*9];
  const int b  = blockIdx.x;
  const int o0 = blockIdx.y * 32;
  const int t  = threadIdx.x;
  const int ol = t & 15, y = t >> 4;
  const bool act_th = (y < HOUT);
  float acc0[WOUT], acc1[WOUT];
  #pragma unroll
  for (int x = 0; x < WOUT; x++){ acc0[x] = 0.f; acc1[x] = 0.f; }
  for (int idx = t; idx < CS*HP*WPL; idx += 256) ((float*)img)[idx] = 0.f;
  const long long inb = (long long)b*Cin*HIN*WIN;
  const int CW9 = Cout*9;
  for (int c0 = 0; c0 < Cin; c0 += CS){
    __syncthreads();
    for (int idx = t; idx < CS*HIN*WIN; idx += 256){
      int cl = idx / (HIN*WIN), r = idx % (HIN*WIN);
      int iy = r / WIN, ix = r % WIN;
      img[cl][(iy+PAD)*WPL + (ix+PAD)] = in[inb + (long long)(c0+cl)*HIN*WIN + r];
    }
    for (int idx = t; idx < CS*288; idx += 256){
      int cl = idx / 288, r = idx % 288;
      wl[cl][r] = wT[(long long)(c0+cl)*CW9 + o0*9 + r];
    }
    __syncthreads();
    if (act_th){
      #pragma unroll
      for (int cl = 0; cl < CS; cl++){
        #pragma unroll
        for (int ky = 0; ky < 3; ky++){
          const float* row = &img[cl][(y+ky)*WPL];
          float rin[NR];
          #pragma unroll
          for (int q = 0; q < NR/4; q++){
            float4 v = ((const float4*)row)[q];
            rin[4*q+0]=v.x; rin[4*q+1]=v.y; rin[4*q+2]=v.z; rin[4*q+3]=v.w;
          }
          #pragma unroll
          for (int x = (NR/4)*4; x < NR; x++) rin[x] = row[x];
          #pragma unroll
          for (int kx = 0; kx < 3; kx++){
            float wv0 = wl[cl][ol*9 + ky*3 + kx];
            float wv1 = wl[cl][(ol+16)*9 + ky*3 + kx];
            #pragma unroll
            for (int x = 0; x < WOUT; x++){
              acc0[x] += wv0 * rin[x+kx];
              acc1[x] += wv1 * rin[x+kx];
            }
          }
        }
      }
    }
  }
  const int og0 = o0 + ol, og1 = o0 + ol + 16;
  float sv0 = 0.f, qv0 = 0.f, sv1 = 0.f, qv1 = 0.f;
  if (act_th){
    float bv0 = bias[og0], bv1 = bias[og1];
    float* po0 = out + (((long long)b*Cout + og0)*HOUT + y)*WOUT;
    float* po1 = out + (((long long)b*Cout + og1)*HOUT + y)*WOUT;
    #pragma unroll
    for (int x = 0; x < WOUT; x++){
      float v0 = acc0[x] + bv0;
      float v1 = acc1[x] + bv1;
      po0[x] = (act == 2) ? eluf(v0) : v0;
      po1[x] = (act == 2) ? eluf(v1) : v1;
      sv0 += v0; qv0 += v0*v0; sv1 += v1; qv1 += v1*v1;
    }
  }
  if (sum){
    sv0 += __shfl_down(sv0, 32); sv0 += __shfl_down(sv0, 16);
    qv0 += __shfl_down(qv0, 32); qv0 += __shfl_down(qv0, 16);
    sv1 += __shfl_down(sv1, 32); sv1 += __shfl_down(sv1, 16);
    qv1 += __shfl_down(qv1, 32); qv1 += __shfl_down(qv1, 16);
    if ((t & 63) < 16){
      atomicAdd(&sum[og0], sv0); atomicAdd(&sq[og0], qv0);
      atomicAdd(&sum[og1], sv1); atomicAdd(&sq[og1], qv1);
    }
  }
}

// ---------------- stride-2 transpose conv, parity-decomposed ----------------
template<int HIN,int WIN,int CIN,int COUT,bool DO_ELU>
__global__ __launch_bounds__(256)
void convt_s2_tiled(const float* __restrict__ in, const float* __restrict__ w,
                    const float* __restrict__ bias, float* __restrict__ out)
{
  constexpr int HOUT = 2*HIN - 1, WOUT = 2*WIN - 1;
  constexpr int RS = 20;
  __shared__ __align__(16) float img[17*RS];
  __shared__ float wl[16][10];
  const int b  = blockIdx.x;
  const int o0 = blockIdx.y * 16;
  const int t  = threadIdx.x;
  const int ol = t & 15, yb = t >> 4;
  for (int idx = t; idx < 17*RS; idx += 256) img[idx] = 0.f;
  float accA[WOUT], accB[WOUT];
  #pragma unroll
  for (int x = 0; x < WOUT; x++){ accA[x] = 0.f; accB[x] = 0.f; }
  for (int c = 0; c < CIN; c++){
    __syncthreads();
    for (int idx = t; idx < HIN*WIN; idx += 256)
      img[(idx/WIN)*RS + idx%WIN] = in[((long long)b*CIN + c)*HIN*WIN + idx];
    if (t < 144)
      wl[t/9][t%9] = w[(((long long)c*COUT + o0 + t/9)*3 + (t%9)/3)*3 + (t%9)%3];
    __syncthreads();
    float ru[16], rd[16];
    #pragma unroll
    for (int q = 0; q < 4; q++){
      float4 va = ((const float4*)&img[yb*RS])[q];
      ru[4*q+0]=va.x; ru[4*q+1]=va.y; ru[4*q+2]=va.z; ru[4*q+3]=va.w;
      float4 vb = ((const float4*)&img[(yb+1)*RS])[q];
      rd[4*q+0]=vb.x; rd[4*q+1]=vb.y; rd[4*q+2]=vb.z; rd[4*q+3]=vb.w;
    }
    float w00=wl[ol][0], w01=wl[ol][1], w02=wl[ol][2];
    float w10=wl[ol][3], w11=wl[ol][4], w12=wl[ol][5];
    float w20=wl[ol][6], w21=wl[ol][7], w22=wl[ol][8];
    #pragma unroll
    for (int v = 0; v < WIN; v++){
      accA[2*v] += w11*ru[v];
      accB[2*v] += w21*ru[v] + w01*rd[v];
    }
    #pragma unroll
    for (int v = 0; v < WIN-1; v++){
      accA[2*v+1] += w12*ru[v] + w10*ru[v+1];
      accB[2*v+1] += w22*ru[v] + w20*ru[v+1] + w02*rd[v] + w00*rd[v+1];
    }
  }
  const int og = o0 + ol;
  const float bv = bias[og];
  const int yA = 2*yb, yB = 2*yb + 1;
  if (yA < HOUT){
    float* po = out + (((long long)b*COUT + og)*HOUT + yA)*WOUT;
    #pragma unroll
    for (int x = 0; x < WOUT; x++){ float v = accA[x] + bv; po[x] = DO_ELU ? eluf(v) : v; }
  }
  if (yB < HOUT){
    float* po = out + (((long long)b*COUT + og)*HOUT + yB)*WOUT;
    #pragma unroll
    for (int x = 0; x < WOUT; x++){ float v = accB[x] + bv; po[x] = DO_ELU ? eluf(v) : v; }
  }
}

// ---------------- deform weight transpose: w[o][c][kk] -> fp32 wT[cc][cl*9+kk][o] ----------------
__global__ void wtrans_kernel(const float* __restrict__ w, float* __restrict__ wT,
                              int CIN, int COUT)
{
  int n = CIN*COUT*9;
  int idx = blockIdx.x*256 + threadIdx.x;
  if (idx >= n) return;
  int cc = idx / (72*COUT);
  int r  = idx % (72*COUT);
  int k  = r / COUT, o = r % COUT;
  int c  = cc*8 + k/9, kk = k%9;
  wT[idx] = w[((long long)o*CIN + c)*9 + kk];
}

// ---------------- deformable conv: gather + register-tiled GEMM, o-split, optional LDS weight stage ----------------
template<int CIN,int COUT,int H,int W,int PXT,int OG,int PG,int COB,bool WSTAGE>
__global__ __launch_bounds__(256)
void deform_gemm(const float* __restrict__ x, const float* __restrict__ om,
                 const float* __restrict__ wT, float* __restrict__ out,
                 float* __restrict__ sum, float* __restrict__ sq)
{
  constexpr int HW = H*W;
  constexpr int NT = (HW + PXT - 1)/PXT;
  constexpr int PXTP = 64;
  constexpr int OT = COB/OG;
  constexpr int PT = PXTP/PG;
  __shared__ __align__(16) float simg[8*HW];
  __shared__ __align__(16) float S[72*PXTP];
  __shared__ __align__(16) float wlds[WSTAGE ? 72*COB : 1];
  __shared__ float kwv[PXT*9*4];
  __shared__ int   kidx[PXT*9*4];
  __shared__ float sred[COB], qred[COB];
  const int tile = blockIdx.x % NT;
  const int b    = blockIdx.x / NT;
  const int obase = blockIdx.y * COB;
  const int t    = threadIdx.x;
  const int og   = t % OG;
  const int pxg  = t / OG;
  const int Hp = H + 2, Wp = W + 2;
  if (t < COB){ sred[t] = 0.f; qred[t] = 0.f; }
  for (int it = t; it < PXT*9; it += 256){
    int px = it / 9, kk = it % 9;
    int p = tile*PXT + px;
    float w0=0.f,w1=0.f,w2=0.f,w3=0.f;
    int i0=0,i1=0,i2=0,i3=0;
    if (p < HW){
      int i = p / W, j = p % W;
      long long base = ((long long)b*27)*HW + p;
      float offx = om[base + (long long)kk*HW];
      float offy = om[base + (long long)(9+kk)*HW];
      float mk   = om[base + (long long)(18+kk)*HW];
      float pnx = (float)(kk/3) - 1.f;
      float pny = (float)(kk%3) - 1.f;
      float px_ = fminf(fmaxf((float)(i+1) + pnx + offx, 0.f), (float)(Hp-1));
      float py_ = fminf(fmaxf((float)(j+1) + pny + offy, 0.f), (float)(Wp-1));
      float fx = floorf(px_), fy = floorf(py_);
      float x0 = fmaxf(fx, 0.f), y0 = fmaxf(fy, 0.f);
      float x1c = fminf(fx + 1.f, (float)(Hp-1));
      float y1c = fminf(fy + 1.f, (float)(Wp-1));
      float glt = (1.f + (x0 - px_)) * (1.f + (y0 - py_));
      float grb = (1.f - (x1c - px_)) * (1.f - (y1c - py_));
      float glb = (1.f + (x0 - px_)) * (1.f - (y1c - py_));
      float grt = (1.f - (x1c - px_)) * (1.f + (y0 - py_));
      int ax0=(int)x0, ay0=(int)y0, ax1=(int)x1c, ay1=(int)y1c;
      if (ax0>=1 && ax0<=H && ay0>=1 && ay0<=W){ w0 = glt*mk; i0 = (ax0-1)*W + (ay0-1); }
      if (ax1>=1 && ax1<=H && ay1>=1 && ay1<=W){ w1 = grb*mk; i1 = (ax1-1)*W + (ay1-1); }
      if (ax0>=1 && ax0<=H && ay1>=1 && ay1<=W){ w2 = glb*mk; i2 = (ax0-1)*W + (ay1-1); }
      if (ax1>=1 && ax1<=H && ay0>=1 && ay0<=W){ w3 = grt*mk; i3 = (ax1-1)*W + (ay0-1); }
    }
    int b4 = it*4;
    kwv[b4+0]=w0; kwv[b4+1]=w1; kwv[b4+2]=w2; kwv[b4+3]=w3;
    kidx[b4+0]=i0; kidx[b4+1]=i1; kidx[b4+2]=i2; kidx[b4+3]=i3;
  }
  float acc[OT][PT];
  #pragma unroll
  for (int oi = 0; oi < OT; oi++)
    #pragma unroll
    for (int pp = 0; pp < PT; pp++) acc[oi][pp] = 0.f;
  for (int cc = 0; cc < CIN/8; cc++){
    __syncthreads();
    for (int idx = t; idx < 8*HW; idx += 256)
      simg[idx] = x[((long long)b*CIN + cc*8)*HW + idx];
    if (WSTAGE){
      for (int idx = t; idx < 72*COB; idx += 256){
        int k = idx / COB, oo = idx % COB;
        wlds[idx] = wT[(long long)cc*72*COUT + k*COUT + obase + oo];
      }
    }
    __syncthreads();
    for (int idx = t; idx < 72*PXTP; idx += 256){
      int k = idx >> 6, px = idx & 63;
      float v = 0.f;
      if (px < PXT){
        int b4 = (px*9 + (k%9))*4;
        const float* im = &simg[(k/9)*HW];
        v = kwv[b4+0]*im[kidx[b4+0]] + kwv[b4+1]*im[kidx[b4+1]]
          + kwv[b4+2]*im[kidx[b4+2]] + kwv[b4+3]*im[kidx[b4+3]];
      }
      S[idx] = v;
    }
    __syncthreads();
    const float* wc = wT + (long long)cc*72*COUT;
    #pragma unroll 2
    for (int k = 0; k < 72; k++){
      float wreg[OT];
      #pragma unroll
      for (int ow = 0; ow < OT/4; ow++){
        float4 wv;
        if (WSTAGE) wv = *(const float4*)(&wlds[k*COB + og*OT + ow*4]);
        else        wv = *(const float4*)(wc + k*COUT + obase + og*OT + ow*4);
        wreg[ow*4+0]=wv.x; wreg[ow*4+1]=wv.y; wreg[ow*4+2]=wv.z; wreg[ow*4+3]=wv.w;
      }
      if constexpr (PT % 4 == 0){
        #pragma unroll
        for (int pq = 0; pq < PT/4; pq++){
          const float4 s4 = *(const float4*)(&S[k*PXTP + pxg*PT + pq*4]);
          #pragma unroll
          for (int oi = 0; oi < OT; oi++){
            acc[oi][pq*4+0] += wreg[oi]*s4.x;
            acc[oi][pq*4+1] += wreg[oi]*s4.y;
            acc[oi][pq*4+2] += wreg[oi]*s4.z;
            acc[oi][pq*4+3] += wreg[oi]*s4.w;
          }
        }
      } else {
        const float2 s2 = *(const float2*)(&S[k*PXTP + pxg*PT]);
        #pragma unroll
        for (int oi = 0; oi < OT; oi++){
          acc[oi][0] += wreg[oi]*s2.x;
          acc[oi][1] += wreg[oi]*s2.y;
        }
      }
    }
  }
  float svl[OT], qvl[OT];
  #pragma unroll
  for (int oi = 0; oi < OT; oi++){ svl[oi] = 0.f; qvl[oi] = 0.f; }
  #pragma unroll
  for (int oi = 0; oi < OT; oi++){
    int o = obase + og*OT + oi;
    #pragma unroll
    for (int pp = 0; pp < PT; pp++){
      int pxl = pxg*PT + pp;
      if (pxl < PXT){
        int p = tile*PXT + pxl;
        if (p < HW){
          float v = acc[oi][pp];
          out[((long long)b*COUT + o)*HW + p] = v;
          svl[oi] += v; qvl[oi] += v*v;
        }
      }
    }
  }
  #pragma unroll
  for (int oi = 0; oi < OT; oi++){
    atomicAdd(&sred[og*OT + oi], svl[oi]);
    atomicAdd(&qred[og*OT + oi], qvl[oi]);
  }
  __syncthreads();
  if (t < COB){ atomicAdd(&sum[obase + t], sred[t]); atomicAdd(&sq[obase + t], qred[t]); }
}

// ---------------- bn + elu + 2x2 avgpool ----------------
__global__ void bn_elu_pool_kernel(const float* __restrict__ in, const float* __restrict__ g,
                                   const float* __restrict__ bb, const float* __restrict__ sum,
                                   const float* __restrict__ sq, float* __restrict__ out,
                                   int B, int C, int H, int W, float invN)
{
  int Ho = H/2, Wo = W/2;
  int idx = blockIdx.x*256 + threadIdx.x;
  int total = B*C*Ho*Wo;
  if (idx >= total) return;
  int x = idx % Wo; int t = idx / Wo;
  int y = t % Ho;   t /= Ho;
  int c = t % C;    int b = t / C;
  float mean = sum[c]*invN;
  float var  = sq[c]*invN - mean*mean;
  float sc = g[c] * rsqrtf(var + 1e-5f);
  float sh = bb[c] - mean*sc;
  const float* p = in + (long long)(b*C + c)*H*W;
  float acc = 0.f;
  #pragma unroll
  for (int dy = 0; dy < 2; dy++)
    #pragma unroll
    for (int dx = 0; dx < 2; dx++)
      acc += eluf(sc*p[(2*y+dy)*W + (2*x+dx)] + sh);
  out[idx] = acc * 0.25f;
}

// ---------------- bn + elu in place ----------------
__global__ void bn_elu_inplace_kernel(float* __restrict__ xio, const float* __restrict__ g,
                                      const float* __restrict__ bb, const float* __restrict__ sum,
                                      const float* __restrict__ sq, int C, int HW, float invN, int total)
{
  int idx = blockIdx.x*256 + threadIdx.x;
  if (idx >= total) return;
  int c = (idx / HW) % C;
  float mean = sum[c]*invN;
  float var  = sq[c]*invN - mean*mean;
  float sc = g[c] * rsqrtf(var + 1e-5f);
  float sh = bb[c] - mean*sc;
  xio[idx] = eluf(sc*xio[idx] + sh);
}

// ---------------- generic transpose conv (kept for convT1m) ----------------
__global__ void convt_kernel(const float* __restrict__ in, const float* __restrict__ w,
                             const float* __restrict__ bias, float* __restrict__ out,
                             int B, int Cin, int Cout, int Hin, int Win, int Hout, int Wout,
                             int K, int S, int PP, int do_elu)
{
  int idx = blockIdx.x*256 + threadIdx.x;
  int total = B*Cout*Hout*Wout;
  if (idx >= total) return;
  int x = idx % Wout; int t = idx / Wout;
  int y = t % Hout;   t /= Hout;
  int o = t % Cout;   int b = t / Cout;
  float acc = bias[o];
  for (int ky = 0; ky < K; ky++){
    int dy = y + ky - PP;
    if (dy < 0 || (dy % S) != 0) continue;
    int iy = dy / S; if (iy >= Hin) continue;
    int wky = K - 1 - ky;
    for (int kx = 0; kx < K; kx++){
      int dx = x + kx - PP;
      if (dx < 0 || (dx % S) != 0) continue;
      int ix = dx / S; if (ix >= Win) continue;
      int wkx = K - 1 - kx;
      const float* ip = in + (long long)b*Cin*Hin*Win + (long long)iy*Win + ix;
      for (int c = 0; c < Cin; c++){
        acc += w[(((long long)c*Cout + o)*K + wky)*K + wkx] * ip[(long long)c*Hin*Win];
      }
    }
  }
  if (do_elu) acc = eluf(acc);
  out[idx] = acc;
}

// ---------------- final bicubic warp ----------------
__device__ __forceinline__ float cubicf(float A, float Bv, float C, float D, float t){
  float a = -0.5f*A + 1.5f*Bv - 1.5f*C + 0.5f*D;
  float b =  A - 2.5f*Bv + 2.0f*C - 0.5f*D;
  float c = -0.5f*A + 0.5f*C;
  return ((a*t + b)*t + c)*t + Bv;
}

__global__ void warp_kernel(const float* __restrict__ V, const float* __restrict__ x1,
                            float* __restrict__ out, int B)
{
  int idx = blockIdx.x*256 + threadIdx.x;
  int total = B*784;
  if (idx >= total) return;
  int j = idx % 28; int t = idx / 28;
  int i = t % 28;   int b = t / 28;
  float v0 = V[((long long)b*2 + 0)*784 + j*28 + i];
  float v1 = V[((long long)b*2 + 1)*784 + j*28 + i];
  float gx = (-1.f + 2.f*(float)j/27.f) + v0;
  float gy = (-1.f + 2.f*(float)i/27.f) + v1;
  float ix = (gx + 1.f)*13.5f;
  float iy = (gy + 1.f)*13.5f;
  float x0 = floorf(ix), y0 = floorf(iy);
  float tx = ix - x0, ty = iy - y0;
  const float* img = x1 + (long long)b*2*784;
  float rows[4];
  #pragma unroll
  for (int ky = -1; ky <= 2; ky++){
    int yi = (int)fminf(fmaxf(y0 + (float)ky, 0.f), 27.f);
    float cv[4];
    #pragma unroll
    for (int kx = -1; kx <= 2; kx++){
      int xi = (int)fminf(fmaxf(x0 + (float)kx, 0.f), 27.f);
      cv[kx+1] = img[yi*28 + xi];
    }
    rows[ky+1] = cubicf(cv[0], cv[1], cv[2], cv[3], tx);
  }
  out[idx] = cubicf(rows[0], rows[1], rows[2], rows[3], ty);
}

// ---------------- host ----------------
extern "C" void kernel_launch(void* const* d_in, const int* in_sizes, int n_in,
                              void* d_out, int out_size, void* d_ws, size_t ws_size,
                              hipStream_t stream)
{
  const int B = 256;
  const float* x1      = (const float*)d_in[0];
  const float* conv1_w = (const float*)d_in[9];
  const float* conv1_b = (const float*)d_in[10];
  const float* bn1_g   = (const float*)d_in[11];
  const float* bn1_b   = (const float*)d_in[12];
  const float* dc2_pw  = (const float*)d_in[13];
  const float* dc2_pb  = (const float*)d_in[14];
  const float* dc2_mw  = (const float*)d_in[15];
  const float* dc2_mb  = (const float*)d_in[16];
  const float* dc2_w   = (const float*)d_in[17];
  const float* bn2_g   = (const float*)d_in[18];
  const float* bn2_b   = (const float*)d_in[19];
  const float* conv3_w = (const float*)d_in[20];
  const float* conv3_b = (const float*)d_in[21];
  const float* bn3_g   = (const float*)d_in[22];
  const float* bn3_b   = (const float*)d_in[23];
  const float* dc41_pw = (const float*)d_in[24];
  const float* dc41_pb = (const float*)d_in[25];
  const float* dc41_mw = (const float*)d_in[26];
  const float* dc41_mb = (const float*)d_in[27];
  const float* dc41_w  = (const float*)d_in[28];
  const float* bn41_g  = (const float*)d_in[29];
  const float* bn41_b  = (const float*)d_in[30];
  const float* conv4_w = (const float*)d_in[31];
  const float* conv4_b = (const float*)d_in[32];
  const float* conv4m_w= (const float*)d_in[33];
  const float* conv4m_b= (const float*)d_in[34];
  const float* conv3m_w= (const float*)d_in[35];
  const float* conv3m_b= (const float*)d_in[36];
  const float* conv2m_w= (const float*)d_in[37];
  const float* conv2m_b= (const float*)d_in[38];
  const float* conv1m_w= (const float*)d_in[39];
  const float* conv1m_b= (const float*)d_in[40];

  float* ws = (float*)d_ws;

  // lifetime-packed arena (floats), stats in [0,1024). (R15-R17 layout — verified)
  const long long AB = 1024;
  float* p1   = ws + AB;
  float* a1   = ws + AB + 3211264;
  float* om2  = ws + AB + 3211264;
  float* a2   = ws + AB + 4566016;
  float* a3   = ws + AB + 10988544;
  float* p2   = ws + AB;
  float* om41 = ws + AB + 1605632;
  float* a41  = ws + AB + 1944320;
  float* a4   = ws + AB + 2747136;
  float* t4m  = ws + AB + 2772224;
  float* t3m  = ws + AB + 8310016;
  float* t2m  = ws + AB + 11996416;
  float* t1m  = ws + AB;
  float* wT2  = ws + AB + 17411072;
  float* wT41 = ws + AB + 17484800;
  float* wT3m = ws + AB + 17705984;
  unsigned short* wb3 = (unsigned short*)(ws + AB + 17779712);

  float* s1  = ws + 0;   float* q1  = ws + 64;
  float* s2  = ws + 128; float* q2  = ws + 256;
  float* s3  = ws + 384; float* q3  = ws + 512;
  float* s41 = ws + 640; float* q41 = ws + 704;

  auto nb = [](long long n){ return (int)((n + 255)/256); };

  hipMemsetAsync(d_ws, 0, 4096, stream);

  // weight pre-transposes / packs
  wtrans_kernel<<<nb(73728), 256, 0, stream>>>(dc2_w,  wT2,  64, 128);
  wtrans_kernel<<<nb(73728), 256, 0, stream>>>(dc41_w, wT41, 128, 64);
  wtrans3_kernel<<<nb(73728), 256, 0, stream>>>(conv3m_w, wT3m, 128, 64, 1);
  wconv3_bf16_kernel<<<nb(147456), 256, 0, stream>>>(conv3_w, wb3);

  // [1] conv1 (2->64, 28x28), fused bn1 stats
  conv1_tiled<<<dim3(B,8), 256, 0, stream>>>(x1, conv1_w, conv1_b, a1, s1, q1);
  // [2] bn1 + elu + avgpool -> p1
  bn_elu_pool_kernel<<<nb((long long)B*64*196), 256, 0, stream>>>(a1, bn1_g, bn1_b, s1, q1, p1,
                                                                  B, 64, 28, 28, 1.f/200704.f);
  // [3] dc2 offsets (64->18) + mask (64->9, sigmoid) -> om2
  conv_tiled<14,14,14,14,1><<<dim3(B,2), 256, 0, stream>>>(p1, dc2_pw, dc2_pb, om2,
                                                           64, 18, 27, 0, 0);
  conv_tiled<14,14,14,14,1><<<dim3(B,1), 256, 0, stream>>>(p1, dc2_mw, dc2_mb, om2,
                                                           64, 9, 27, 18, 1);
  // [4] deform conv 2 (64->128) -> a2, fused bn2 stats; 4o x 8px register tile (R17-proven)
  deform_gemm<64,128,14,14,49,32,8,128,false><<<dim3(B*4,1), 256, 0, stream>>>(p1, om2, wT2, a2, s2, q2);
  // [5] bn2 + elu
  bn_elu_inplace_kernel<<<nb((long long)B*128*196), 256, 0, stream>>>(a2, bn2_g, bn2_b, s2, q2,
                                                                      128, 196, 1.f/50176.f, B*128*196);
  // [6] conv3 (128->128) -> a3 via bf16 MFMA, fused bn3 stats
  conv3_mfma<<<dim3(B,8), 256, 0, stream>>>(a2, wb3, conv3_b, a3, s3, q3);
  // [7] bn3 + elu + avgpool -> p2
  bn_elu_pool_kernel<<<nb((long long)B*128*49), 256, 0, stream>>>(a3, bn3_g, bn3_b, s3, q3, p2,
                                                                  B, 128, 14, 14, 1.f/50176.f);
  // [8] dc41 offsets + mask -> om41
  conv_tiled<7,7,7,7,1><<<dim3(B,2), 256, 0, stream>>>(p2, dc41_pw, dc41_pb, om41,
                                                       128, 18, 27, 0, 0);
  conv_tiled<7,7,7,7,1><<<dim3(B,1), 256, 0, stream>>>(p2, dc41_mw, dc41_mb, om41,
                                                       128, 9, 27, 18, 1);
  // [9] deform conv 41 (128->64) -> a41, fused bn41 stats; o-split x2 + fp32 LDS weight stage
  deform_gemm<128,64,7,7,49,8,32,32,true><<<dim3(B,2), 256, 0, stream>>>(p2, om41, wT41, a41, s41, q41);
  // [10] bn41 + elu
  bn_elu_inplace_kernel<<<nb((long long)B*64*49), 256, 0, stream>>>(a41, bn41_g, bn41_b, s41, q41,
                                                                    64, 49, 1.f/12544.f, B*64*49);
  // [11] conv4 (64->2, 7x7) naive (tiny)
  conv3x3_kernel<<<nb((long long)B*2*49), 256, 0, stream>>>(a41, conv4_w, conv4_b, a4,
                                                            B, 64, 2, 7, 7, 2, 0, 0);
  // [12] convT4m: 2->128, s=2, p=1, 7->13, parity-decomposed
  convt_s2_tiled<7,7,2,128,false><<<dim3(B,8), 256, 0, stream>>>(a4, conv4m_w, conv4m_b, t4m);
  // [13] convT3m: 128->64, s=1 == conv pad2 flipped (pre-transposed), 32-o tile, CS=2, +elu
  conv_tiled_w2<13,13,15,15,2,2><<<dim3(B,2), 256, 0, stream>>>(t4m, wT3m, conv3m_b, t3m,
                                                                nullptr, nullptr, 128, 64, 2);
  // [14] convT2m: 64->32, s=2, p=1, 15->29, +elu, parity-decomposed
  convt_s2_tiled<15,15,64,32,true><<<dim3(B,2), 256, 0, stream>>>(t3m, conv2m_w, conv2m_b, t2m);
  // [15] convT1m: 32->2, k=2, s=1, p=1, 29->28, +elu (naive, tiny)
  convt_kernel<<<nb((long long)B*2*784), 256, 0, stream>>>(t2m, conv1m_w, conv1m_b, t1m,
                                                           B, 32, 2, 29, 29, 28, 28, 2, 1, 0, 1);
  // [16] final warp
  warp_kernel<<<nb((long long)B*784), 256, 0, stream>>>(t1m, x1, (float*)d_out, B);
}

// Round 23
// 1301.366 us; speedup vs baseline: 1.0663x; 1.0146x over previous
//
#include <hip/hip_runtime.h>
#include <hip/hip_bf16.h>

__device__ __forceinline__ float eluf(float x){ return x > 0.f ? x : expm1f(x); }

typedef __attribute__((ext_vector_type(8))) short bf16x8;
typedef __attribute__((ext_vector_type(4))) float f32x4;

__device__ __forceinline__ unsigned int bf16r(float f){
  unsigned int u = __float_as_uint(f);
  return (u + 0x7FFFu + ((u >> 16) & 1u)) >> 16;   // RNE
}

// LDS row stride helper
constexpr int pad_stride(int wp){
  int s = (wp + 3) & ~3;
  return (s % 8 == 0) ? s + 4 : s;
}

// ---------------- naive 3x3 pad-1 conv (kept only for tiny conv4) ----------------
__global__ void conv3x3_kernel(const float* __restrict__ in, const float* __restrict__ w,
                               const float* __restrict__ bias, float* __restrict__ out,
                               int B, int Cin, int Cout, int H, int W, int Ctot, int ooff, int act)
{
  int idx = blockIdx.x*256 + threadIdx.x;
  int total = B*Cout*H*W;
  if (idx >= total) return;
  int x = idx % W; int t = idx / W;
  int y = t % H;   t /= H;
  int o = t % Cout; int b = t / Cout;
  float acc = bias ? bias[o] : 0.f;
  const float* wp = w + (long long)o*Cin*9;
  for (int c = 0; c < Cin; c++){
    const float* ip = in + (long long)(b*Cin + c)*H*W;
    const float* wc = wp + c*9;
    #pragma unroll
    for (int ky = 0; ky < 3; ky++){
      int iy = y + ky - 1; if ((unsigned)iy >= (unsigned)H) continue;
      #pragma unroll
      for (int kx = 0; kx < 3; kx++){
        int ix = x + kx - 1; if ((unsigned)ix >= (unsigned)W) continue;
        acc += wc[ky*3+kx] * ip[iy*W + ix];
      }
    }
  }
  if (act == 1) acc = 1.f/(1.f + expf(-acc));
  out[(((long long)b*Ctot + ooff + o)*H + y)*W + x] = acc;
}

// ---------------- conv1: 2->64, 28x28, fused bn-stats ----------------
__global__ __launch_bounds__(256)
void conv1_tiled(const float* __restrict__ in, const float* __restrict__ w,
                 const float* __restrict__ bias, float* __restrict__ out,
                 float* __restrict__ sum, float* __restrict__ sq)
{
  constexpr int WPL = pad_stride(30);   // 36
  __shared__ __align__(16) float img[2][30*WPL];
  __shared__ float wl[2][8*9];
  const int b = blockIdx.x, o0 = blockIdx.y*8, t = threadIdx.x;
  const int ol = t & 7, y = t >> 3;
  for (int idx = t; idx < 2*30*WPL; idx += 256) ((float*)img)[idx] = 0.f;
  __syncthreads();
  for (int idx = t; idx < 2*784; idx += 256){
    int cl = idx/784, r = idx%784;
    img[cl][(r/28 + 1)*WPL + (r%28) + 1] = in[((long long)b*2)*784 + idx];
  }
  if (t < 144){
    int cl = t/72, r = t%72;
    wl[cl][r] = w[(((long long)(o0 + r/9))*2 + cl)*9 + (r%9)];
  }
  __syncthreads();
  const bool active = (y < 28);
  float acc[28];
  #pragma unroll
  for (int x = 0; x < 28; x++) acc[x] = 0.f;
  if (active){
    for (int cl = 0; cl < 2; cl++){
      #pragma unroll
      for (int ky = 0; ky < 3; ky++){
        const float* row = &img[cl][(y+ky)*WPL];
        float rin[30];
        #pragma unroll
        for (int q = 0; q < 7; q++){
          float4 v = ((const float4*)row)[q];
          rin[4*q+0]=v.x; rin[4*q+1]=v.y; rin[4*q+2]=v.z; rin[4*q+3]=v.w;
        }
        rin[28] = row[28]; rin[29] = row[29];
        #pragma unroll
        for (int kx = 0; kx < 3; kx++){
          float wv = wl[cl][ol*9 + ky*3 + kx];
          #pragma unroll
          for (int x = 0; x < 28; x++) acc[x] += wv * rin[x+kx];
        }
      }
    }
  }
  const int og = o0 + ol;
  float sv = 0.f, qv = 0.f;
  if (active){
    float bv = bias[og];
    float* po = out + (((long long)b*64 + og)*28 + y)*28;
    #pragma unroll
    for (int x = 0; x < 28; x++){
      float v = acc[x] + bv;
      po[x] = v;
      sv += v; qv += v*v;
    }
  }
  #pragma unroll
  for (int d = 32; d >= 8; d >>= 1){
    sv += __shfl_down(sv, d);
    qv += __shfl_down(qv, d);
  }
  if ((t & 63) < 8){ atomicAdd(&sum[og], sv); atomicAdd(&sq[og], qv); }
}

// ---------------- tiled 3x3 conv, CS=1, 16-o tile (for small Cout convs) ----------------
template<int HIN,int WIN,int HOUT,int WOUT,int PAD>
__global__ __launch_bounds__(256)
void conv_tiled(const float* __restrict__ in, const float* __restrict__ w,
                const float* __restrict__ bias, float* __restrict__ out,
                int Cin, int Cout, int Ctot, int ooff, int act)
{
  constexpr int HP = HIN + 2*PAD, WP = WIN + 2*PAD, WPL = pad_stride(WP);
  constexpr int NR = WOUT + 2;
  __shared__ __align__(16) float img[HP*WPL];
  __shared__ float wl[16*9];
  const int b  = blockIdx.x;
  const int o0 = blockIdx.y * 16;
  const int t  = threadIdx.x;
  const int ol = t & 15, y = t >> 4;
  const bool act_th = (y < HOUT) && (o0 + ol < Cout);
  float acc[WOUT];
  #pragma unroll
  for (int x = 0; x < WOUT; x++) acc[x] = 0.f;
  for (int idx = t; idx < HP*WPL; idx += 256) img[idx] = 0.f;
  const long long inb = (long long)b*Cin*HIN*WIN;
  for (int c = 0; c < Cin; c++){
    __syncthreads();
    for (int idx = t; idx < HIN*WIN; idx += 256){
      int iy = idx / WIN, ix = idx % WIN;
      img[(iy+PAD)*WPL + (ix+PAD)] = in[inb + (long long)c*HIN*WIN + idx];
    }
    if (t < 144){
      int oo = t / 9, kk = t % 9;
      int og = o0 + oo;
      wl[t] = (og < Cout) ? w[((long long)og*Cin + c)*9 + kk] : 0.f;
    }
    __syncthreads();
    if (act_th){
      #pragma unroll
      for (int ky = 0; ky < 3; ky++){
        const float* row = &img[(y+ky)*WPL];
        float rin[NR];
        #pragma unroll
        for (int q = 0; q < NR/4; q++){
          float4 v = ((const float4*)row)[q];
          rin[4*q+0]=v.x; rin[4*q+1]=v.y; rin[4*q+2]=v.z; rin[4*q+3]=v.w;
        }
        #pragma unroll
        for (int x = (NR/4)*4; x < NR; x++) rin[x] = row[x];
        #pragma unroll
        for (int kx = 0; kx < 3; kx++){
          float wv = wl[ol*9 + ky*3 + kx];
          #pragma unroll
          for (int x = 0; x < WOUT; x++) acc[x] += wv * rin[x+kx];
        }
      }
    }
  }
  if (act_th){
    int og = o0 + ol;
    float bv = bias[og];
    #pragma unroll
    for (int x = 0; x < WOUT; x++){
      float v = acc[x] + bv;
      if (act == 1) v = 1.f/(1.f + expf(-v));
      else if (act == 2) v = eluf(v);
      out[(((long long)b*Ctot + ooff + og)*HOUT + y)*WOUT + x] = v;
    }
  }
}

// ---------------- conv weight transpose: -> wT[c][o*9+kk] (flip for transpose-conv) ----------------
__global__ void wtrans3_kernel(const float* __restrict__ w, float* __restrict__ wT,
                               int Cin, int Cout, int flip)
{
  int n = Cin*Cout*9;
  int idx = blockIdx.x*256 + threadIdx.x;
  if (idx >= n) return;
  int c  = idx / (Cout*9);
  int r  = idx % (Cout*9);
  int o  = r / 9, kk = r % 9;
  float v;
  if (flip) v = w[((long long)c*Cout + o)*9 + (2 - kk/3)*3 + (2 - kk%3)];
  else      v = w[((long long)o*Cin + c)*9 + kk];
  wT[idx] = v;
}

// ---------------- conv3 weights -> bf16 wb[kk][o][c] ----------------
__global__ void wconv3_bf16_kernel(const float* __restrict__ w, unsigned short* __restrict__ wb)
{
  int idx = blockIdx.x*256 + threadIdx.x;
  if (idx >= 147456) return;
  int kk = idx >> 14;
  int r  = idx & 16383;
  int o  = r >> 7, c = r & 127;
  wb[idx] = (unsigned short)bf16r(w[((long long)o*128 + c)*9 + kk]);
}

// ---------------- conv3 via bf16 MFMA (shift-decomposed implicit GEMM) ----------------
__global__ __launch_bounds__(256)
void conv3_mfma(const float* __restrict__ in, const unsigned short* __restrict__ wb,
                const float* __restrict__ bias, float* __restrict__ out,
                float* __restrict__ sum, float* __restrict__ sq)
{
  constexpr int RS = 88;                   // u16 per hp row (64 ch + 24 pad) = 176 B
  __shared__ unsigned short img[256*RS];
  __shared__ float sred[16], qred[16];
  const int b  = blockIdx.x;
  const int o0 = blockIdx.y * 16;
  const int t  = threadIdx.x;
  const int lane = t & 63;
  const int wv = t >> 6;
  const int l15 = lane & 15, q = lane >> 4;
  if (t < 16){ sred[t] = 0.f; qred[t] = 0.f; }
  const int ntile = (wv == 0) ? 4 : 3;
  f32x4 acc[4];
  #pragma unroll
  for (int i = 0; i < 4; i++) acc[i] = (f32x4){0.f,0.f,0.f,0.f};
  for (int idx = t; idx < 256*RS/2; idx += 256) ((unsigned int*)img)[idx] = 0u;
  const long long inb = (long long)b*128*196;
  for (int ch = 0; ch < 2; ch++){
    __syncthreads();
    for (int idx = t; idx < 32*196; idx += 256){
      int c2 = idx / 196, px = idx % 196;
      int c = 2*c2;
      float f0 = in[inb + (long long)(ch*64 + c)*196 + px];
      float f1 = in[inb + (long long)(ch*64 + c + 1)*196 + px];
      int hp = (px/14 + 1)*16 + (px%14) + 1;
      *(unsigned int*)&img[hp*RS + c] = bf16r(f0) | (bf16r(f1) << 16);
    }
    __syncthreads();
    for (int ti = 0; ti < ntile; ti++){
      int tile = wv + ti*4;
      int px = tile*16 + l15;
      int pxe = px < 196 ? px : 195;
      int base = (pxe/14)*16 + (pxe%14);
      #pragma unroll
      for (int kk = 0; kk < 9; kk++){
        int hp = base + (kk/3)*16 + (kk%3);
        #pragma unroll
        for (int ks = 0; ks < 2; ks++){
          bf16x8 bfrag = *(const bf16x8*)&img[hp*RS + ks*32 + q*8];
          const unsigned short* wp = wb + (((long long)kk*128 + o0 + l15)*128 + ch*64 + ks*32 + q*8);
          bf16x8 afrag = *(const bf16x8*)wp;
          acc[ti] = __builtin_amdgcn_mfma_f32_16x16x32_bf16(afrag, bfrag, acc[ti], 0, 0, 0);
        }
      }
    }
  }
  float svl[4], qvl[4];
  #pragma unroll
  for (int r = 0; r < 4; r++){ svl[r] = 0.f; qvl[r] = 0.f; }
  for (int ti = 0; ti < ntile; ti++){
    int tile = wv + ti*4;
    int px = tile*16 + l15;
    if (px < 196){
      #pragma unroll
      for (int r = 0; r < 4; r++){
        int ol = q*4 + r;
        float v = acc[ti][r] + bias[o0 + ol];
        out[((long long)b*128 + o0 + ol)*196 + px] = v;
        svl[r] += v; qvl[r] += v*v;
      }
    }
  }
  #pragma unroll
  for (int r = 0; r < 4; r++){
    #pragma unroll
    for (int m = 1; m < 16; m <<= 1){
      svl[r] += __shfl_xor(svl[r], m);
      qvl[r] += __shfl_xor(qvl[r], m);
    }
  }
  if (l15 == 0){
    #pragma unroll
    for (int r = 0; r < 4; r++){
      atomicAdd(&sred[q*4 + r], svl[r]);
      atomicAdd(&qred[q*4 + r], qvl[r]);
    }
  }
  __syncthreads();
  if (t < 16){ atomicAdd(&sum[o0 + t], sred[t]); atomicAdd(&sq[o0 + t], qred[t]); }
}

// ---------------- tiled 3x3 conv, CS channels/barrier, 32-o tile, wT weights, channel-split ----------------
// grid (B, Cout/32, NZ). z-block handles Cin/NZ channels; z==0 adds bias -> out, z>0 -> out2 partial.
template<int HIN,int WIN,int HOUT,int WOUT,int PAD,int CS,int NZ>
__global__ __launch_bounds__(256)
void conv_tiled_w2(const float* __restrict__ in, const float* __restrict__ wT,
                   const float* __restrict__ bias, float* __restrict__ out,
                   float* __restrict__ out2, int Cin, int Cout)
{
  constexpr int HP = HIN + 2*PAD, WP = WIN + 2*PAD, WPL = pad_stride(WP);
  constexpr int NR = WOUT + 2;
  __shared__ __align__(16) float img[CS][HP*WPL];
  __shared__ float wl[CS][32*9];
  const int b  = blockIdx.x;
  const int o0 = blockIdx.y * 32;
  const int z  = blockIdx.z;
  const int t  = threadIdx.x;
  const int ol = t & 15, y = t >> 4;
  const bool act_th = (y < HOUT);
  float acc0[WOUT], acc1[WOUT];
  #pragma unroll
  for (int x = 0; x < WOUT; x++){ acc0[x] = 0.f; acc1[x] = 0.f; }
  for (int idx = t; idx < CS*HP*WPL; idx += 256) ((float*)img)[idx] = 0.f;
  const long long inb = (long long)b*Cin*HIN*WIN;
  const int CW9 = Cout*9;
  const int cbase = z * (Cin/NZ);
  const int cend  = cbase + Cin/NZ;
  for (int c0 = cbase; c0 < cend; c0 += CS){
    __syncthreads();
    for (int idx = t; idx < CS*HIN*WIN; idx += 256){
      int cl = idx / (HIN*WIN), r = idx % (HIN*WIN);
      int iy = r / WIN, ix = r % WIN;
      img[cl][(iy+PAD)*WPL + (ix+PAD)] = in[inb + (long long)(c0+cl)*HIN*WIN + r];
    }
    for (int idx = t; idx < CS*288; idx += 256){
      int cl = idx / 288, r = idx % 288;
      wl[cl][r] = wT[(long long)(c0+cl)*CW9 + o0*9 + r];
    }
    __syncthreads();
    if (act_th){
      #pragma unroll
      for (int cl = 0; cl < CS; cl++){
        #pragma unroll
        for (int ky = 0; ky < 3; ky++){
          const float* row = &img[cl][(y+ky)*WPL];
          float rin[NR];
          #pragma unroll
          for (int q = 0; q < NR/4; q++){
            float4 v = ((const float4*)row)[q];
            rin[4*q+0]=v.x; rin[4*q+1]=v.y; rin[4*q+2]=v.z; rin[4*q+3]=v.w;
          }
          #pragma unroll
          for (int x = (NR/4)*4; x < NR; x++) rin[x] = row[x];
          #pragma unroll
          for (int kx = 0; kx < 3; kx++){
            float wv0 = wl[cl][ol*9 + ky*3 + kx];
            float wv1 = wl[cl][(ol+16)*9 + ky*3 + kx];
            #pragma unroll
            for (int x = 0; x < WOUT; x++){
              acc0[x] += wv0 * rin[x+kx];
              acc1[x] += wv1 * rin[x+kx];
            }
          }
        }
      }
    }
  }
  if (act_th){
    const int og0 = o0 + ol, og1 = o0 + ol + 16;
    float bv0 = (z == 0) ? bias[og0] : 0.f;
    float bv1 = (z == 0) ? bias[og1] : 0.f;
    float* dst = (z == 0) ? out : out2;
    float* po0 = dst + (((long long)b*Cout + og0)*HOUT + y)*WOUT;
    float* po1 = dst + (((long long)b*Cout + og1)*HOUT + y)*WOUT;
    #pragma unroll
    for (int x = 0; x < WOUT; x++){
      po0[x] = acc0[x] + bv0;
      po1[x] = acc1[x] + bv1;
    }
  }
}

// ---------------- a = elu(a + b) combine ----------------
__global__ void add_elu_kernel(float* __restrict__ a, const float* __restrict__ b, int n)
{
  int i = blockIdx.x*256 + threadIdx.x;
  if (i < n) a[i] = eluf(a[i] + b[i]);
}

// ---------------- stride-2 transpose conv, parity-decomposed ----------------
template<int HIN,int WIN,int CIN,int COUT,bool DO_ELU>
__global__ __launch_bounds__(256)
void convt_s2_tiled(const float* __restrict__ in, const float* __restrict__ w,
                    const float* __restrict__ bias, float* __restrict__ out)
{
  constexpr int HOUT = 2*HIN - 1, WOUT = 2*WIN - 1;
  constexpr int RS = 20;
  __shared__ __align__(16) float img[17*RS];
  __shared__ float wl[16][10];
  const int b  = blockIdx.x;
  const int o0 = blockIdx.y * 16;
  const int t  = threadIdx.x;
  const int ol = t & 15, yb = t >> 4;
  for (int idx = t; idx < 17*RS; idx += 256) img[idx] = 0.f;
  float accA[WOUT], accB[WOUT];
  #pragma unroll
  for (int x = 0; x < WOUT; x++){ accA[x] = 0.f; accB[x] = 0.f; }
  for (int c = 0; c < CIN; c++){
    __syncthreads();
    for (int idx = t; idx < HIN*WIN; idx += 256)
      img[(idx/WIN)*RS + idx%WIN] = in[((long long)b*CIN + c)*HIN*WIN + idx];
    if (t < 144)
      wl[t/9][t%9] = w[(((long long)c*COUT + o0 + t/9)*3 + (t%9)/3)*3 + (t%9)%3];
    __syncthreads();
    float ru[16], rd[16];
    #pragma unroll
    for (int q = 0; q < 4; q++){
      float4 va = ((const float4*)&img[yb*RS])[q];
      ru[4*q+0]=va.x; ru[4*q+1]=va.y; ru[4*q+2]=va.z; ru[4*q+3]=va.w;
      float4 vb = ((const float4*)&img[(yb+1)*RS])[q];
      rd[4*q+0]=vb.x; rd[4*q+1]=vb.y; rd[4*q+2]=vb.z; rd[4*q+3]=vb.w;
    }
    float w00=wl[ol][0], w01=wl[ol][1], w02=wl[ol][2];
    float w10=wl[ol][3], w11=wl[ol][4], w12=wl[ol][5];
    float w20=wl[ol][6], w21=wl[ol][7], w22=wl[ol][8];
    #pragma unroll
    for (int v = 0; v < WIN; v++){
      accA[2*v] += w11*ru[v];
      accB[2*v] += w21*ru[v] + w01*rd[v];
    }
    #pragma unroll
    for (int v = 0; v < WIN-1; v++){
      accA[2*v+1] += w12*ru[v] + w10*ru[v+1];
      accB[2*v+1] += w22*ru[v] + w20*ru[v+1] + w02*rd[v] + w00*rd[v+1];
    }
  }
  const int og = o0 + ol;
  const float bv = bias[og];
  const int yA = 2*yb, yB = 2*yb + 1;
  if (yA < HOUT){
    float* po = out + (((long long)b*COUT + og)*HOUT + yA)*WOUT;
    #pragma unroll
    for (int x = 0; x < WOUT; x++){ float v = accA[x] + bv; po[x] = DO_ELU ? eluf(v) : v; }
  }
  if (yB < HOUT){
    float* po = out + (((long long)b*COUT + og)*HOUT + yB)*WOUT;
    #pragma unroll
    for (int x = 0; x < WOUT; x++){ float v = accB[x] + bv; po[x] = DO_ELU ? eluf(v) : v; }
  }
}

// ---------------- deform weight transpose: w[o][c][kk] -> fp32 wT[cc][cl*9+kk][o] ----------------
__global__ void wtrans_kernel(const float* __restrict__ w, float* __restrict__ wT,
                              int CIN, int COUT)
{
  int n = CIN*COUT*9;
  int idx = blockIdx.x*256 + threadIdx.x;
  if (idx >= n) return;
  int cc = idx / (72*COUT);
  int r  = idx % (72*COUT);
  int k  = r / COUT, o = r % COUT;
  int c  = cc*8 + k/9, kk = k%9;
  wT[idx] = w[((long long)o*CIN + c)*9 + kk];
}

// ---------------- deformable conv: gather + register-tiled GEMM, o-split, optional LDS weight stage ----------------
template<int CIN,int COUT,int H,int W,int PXT,int OG,int PG,int COB,bool WSTAGE>
__global__ __launch_bounds__(256)
void deform_gemm(const float* __restrict__ x, const float* __restrict__ om,
                 const float* __restrict__ wT, float* __restrict__ out,
                 float* __restrict__ sum, float* __restrict__ sq)
{
  constexpr int HW = H*W;
  constexpr int NT = (HW + PXT - 1)/PXT;
  constexpr int PXTP = 64;
  constexpr int OT = COB/OG;
  constexpr int PT = PXTP/PG;
  __shared__ __align__(16) float simg[8*HW];
  __shared__ __align__(16) float S[72*PXTP];
  __shared__ __align__(16) float wlds[WSTAGE ? 72*COB : 1];
  __shared__ float kwv[PXT*9*4];
  __shared__ int   kidx[PXT*9*4];
  __shared__ float sred[COB], qred[COB];
  const int tile = blockIdx.x % NT;
  const int b    = blockIdx.x / NT;
  const int obase = blockIdx.y * COB;
  const int t    = threadIdx.x;
  const int og   = t % OG;
  const int pxg  = t / OG;
  const int Hp = H + 2, Wp = W + 2;
  if (t < COB){ sred[t] = 0.f; qred[t] = 0.f; }
  for (int it = t; it < PXT*9; it += 256){
    int px = it / 9, kk = it % 9;
    int p = tile*PXT + px;
    float w0=0.f,w1=0.f,w2=0.f,w3=0.f;
    int i0=0,i1=0,i2=0,i3=0;
    if (p < HW){
      int i = p / W, j = p % W;
      long long base = ((long long)b*27)*HW + p;
      float offx = om[base + (long long)kk*HW];
      float offy = om[base + (long long)(9+kk)*HW];
      float mk   = om[base + (long long)(18+kk)*HW];
      float pnx = (float)(kk/3) - 1.f;
      float pny = (float)(kk%3) - 1.f;
      float px_ = fminf(fmaxf((float)(i+1) + pnx + offx, 0.f), (float)(Hp-1));
      float py_ = fminf(fmaxf((float)(j+1) + pny + offy, 0.f), (float)(Wp-1));
      float fx = floorf(px_), fy = floorf(py_);
      float x0 = fmaxf(fx, 0.f), y0 = fmaxf(fy, 0.f);
      float x1c = fminf(fx + 1.f, (float)(Hp-1));
      float y1c = fminf(fy + 1.f, (float)(Wp-1));
      float glt = (1.f + (x0 - px_)) * (1.f + (y0 - py_));
      float grb = (1.f - (x1c - px_)) * (1.f - (y1c - py_));
      float glb = (1.f + (x0 - px_)) * (1.f - (y1c - py_));
      float grt = (1.f - (x1c - px_)) * (1.f + (y0 - py_));
      int ax0=(int)x0, ay0=(int)y0, ax1=(int)x1c, ay1=(int)y1c;
      if (ax0>=1 && ax0<=H && ay0>=1 && ay0<=W){ w0 = glt*mk; i0 = (ax0-1)*W + (ay0-1); }
      if (ax1>=1 && ax1<=H && ay1>=1 && ay1<=W){ w1 = grb*mk; i1 = (ax1-1)*W + (ay1-1); }
      if (ax0>=1 && ax0<=H && ay1>=1 && ay1<=W){ w2 = glb*mk; i2 = (ax0-1)*W + (ay1-1); }
      if (ax1>=1 && ax1<=H && ay0>=1 && ay0<=W){ w3 = grt*mk; i3 = (ax1-1)*W + (ay0-1); }
    }
    int b4 = it*4;
    kwv[b4+0]=w0; kwv[b4+1]=w1; kwv[b4+2]=w2; kwv[b4+3]=w3;
    kidx[b4+0]=i0; kidx[b4+1]=i1; kidx[b4+2]=i2; kidx[b4+3]=i3;
  }
  float acc[OT][PT];
  #pragma unroll
  for (int oi = 0; oi < OT; oi++)
    #pragma unroll
    for (int pp = 0; pp < PT; pp++) acc[oi][pp] = 0.f;
  for (int cc = 0; cc < CIN/8; cc++){
    __syncthreads();
    for (int idx = t; idx < 8*HW; idx += 256)
      simg[idx] = x[((long long)b*CIN + cc*8)*HW + idx];
    if (WSTAGE){
      for (int idx = t; idx < 72*COB; idx += 256){
        int k = idx / COB, oo = idx % COB;
        wlds[idx] = wT[(long long)cc*72*COUT + k*COUT + obase + oo];
      }
    }
    __syncthreads();
    for (int idx = t; idx < 72*PXTP; idx += 256){
      int k = idx >> 6, px = idx & 63;
      float v = 0.f;
      if (px < PXT){
        int b4 = (px*9 + (k%9))*4;
        const float* im = &simg[(k/9)*HW];
        v = kwv[b4+0]*im[kidx[b4+0]] + kwv[b4+1]*im[kidx[b4+1]]
          + kwv[b4+2]*im[kidx[b4+2]] + kwv[b4+3]*im[kidx[b4+3]];
      }
      S[idx] = v;
    }
    __syncthreads();
    const float* wc = wT + (long long)cc*72*COUT;
    #pragma unroll 2
    for (int k = 0; k < 72; k++){
      float wreg[OT];
      #pragma unroll
      for (int ow = 0; ow < OT/4; ow++){
        float4 wv;
        if (WSTAGE) wv = *(const float4*)(&wlds[k*COB + og*OT + ow*4]);
        else        wv = *(const float4*)(wc + k*COUT + obase + og*OT + ow*4);
        wreg[ow*4+0]=wv.x; wreg[ow*4+1]=wv.y; wreg[ow*4+2]=wv.z; wreg[ow*4+3]=wv.w;
      }
      if constexpr (PT % 4 == 0){
        #pragma unroll
        for (int pq = 0; pq < PT/4; pq++){
          const float4 s4 = *(const float4*)(&S[k*PXTP + pxg*PT + pq*4]);
          #pragma unroll
          for (int oi = 0; oi < OT; oi++){
            acc[oi][pq*4+0] += wreg[oi]*s4.x;
            acc[oi][pq*4+1] += wreg[oi]*s4.y;
            acc[oi][pq*4+2] += wreg[oi]*s4.z;
            acc[oi][pq*4+3] += wreg[oi]*s4.w;
          }
        }
      } else {
        const float2 s2 = *(const float2*)(&S[k*PXTP + pxg*PT]);
        #pragma unroll
        for (int oi = 0; oi < OT; oi++){
          acc[oi][0] += wreg[oi]*s2.x;
          acc[oi][1] += wreg[oi]*s2.y;
        }
      }
    }
  }
  float svl[OT], qvl[OT];
  #pragma unroll
  for (int oi = 0; oi < OT; oi++){ svl[oi] = 0.f; qvl[oi] = 0.f; }
  #pragma unroll
  for (int oi = 0; oi < OT; oi++){
    int o = obase + og*OT + oi;
    #pragma unroll
    for (int pp = 0; pp < PT; pp++){
      int pxl = pxg*PT + pp;
      if (pxl < PXT){
        int p = tile*PXT + pxl;
        if (p < HW){
          float v = acc[oi][pp];
          out[((long long)b*COUT + o)*HW + p] = v;
          svl[oi] += v; qvl[oi] += v*v;
        }
      }
    }
  }
  #pragma unroll
  for (int oi = 0; oi < OT; oi++){
    atomicAdd(&sred[og*OT + oi], svl[oi]);
    atomicAdd(&qred[og*OT + oi], qvl[oi]);
  }
  __syncthreads();
  if (t < COB){ atomicAdd(&sum[obase + t], sred[t]); atomicAdd(&sq[obase + t], qred[t]); }
}

// ---------------- bn + elu + 2x2 avgpool ----------------
__global__ void bn_elu_pool_kernel(const float* __restrict__ in, const float* __restrict__ g,
                                   const float* __restrict__ bb, const float* __restrict__ sum,
                                   const float* __restrict__ sq, float* __restrict__ out,
                                   int B, int C, int H, int W, float invN)
{
  int Ho = H/2, Wo = W/2;
  int idx = blockIdx.x*256 + threadIdx.x;
  int total = B*C*Ho*Wo;
  if (idx >= total) return;
  int x = idx % Wo; int t = idx / Wo;
  int y = t % Ho;   t /= Ho;
  int c = t % C;    int b = t / C;
  float mean = sum[c]*invN;
  float var  = sq[c]*invN - mean*mean;
  float sc = g[c] * rsqrtf(var + 1e-5f);
  float sh = bb[c] - mean*sc;
  const float* p = in + (long long)(b*C + c)*H*W;
  float acc = 0.f;
  #pragma unroll
  for (int dy = 0; dy < 2; dy++)
    #pragma unroll
    for (int dx = 0; dx < 2; dx++)
      acc += eluf(sc*p[(2*y+dy)*W + (2*x+dx)] + sh);
  out[idx] = acc * 0.25f;
}

// ---------------- bn + elu in place ----------------
__global__ void bn_elu_inplace_kernel(float* __restrict__ xio, const float* __restrict__ g,
                                      const float* __restrict__ bb, const float* __restrict__ sum,
                                      const float* __restrict__ sq, int C, int HW, float invN, int total)
{
  int idx = blockIdx.x*256 + threadIdx.x;
  if (idx >= total) return;
  int c = (idx / HW) % C;
  float mean = sum[c]*invN;
  float var  = sq[c]*invN - mean*mean;
  float sc = g[c] * rsqrtf(var + 1e-5f);
  float sh = bb[c] - mean*sc;
  xio[idx] = eluf(sc*xio[idx] + sh);
}

// ---------------- generic transpose conv (kept for convT1m) ----------------
__global__ void convt_kernel(const float* __restrict__ in, const float* __restrict__ w,
                             const float* __restrict__ bias, float* __restrict__ out,
                             int B, int Cin, int Cout, int Hin, int Win, int Hout, int Wout,
                             int K, int S, int PP, int do_elu)
{
  int idx = blockIdx.x*256 + threadIdx.x;
  int total = B*Cout*Hout*Wout;
  if (idx >= total) return;
  int x = idx % Wout; int t = idx / Wout;
  int y = t % Hout;   t /= Hout;
  int o = t % Cout;   int b = t / Cout;
  float acc = bias[o];
  for (int ky = 0; ky < K; ky++){
    int dy = y + ky - PP;
    if (dy < 0 || (dy % S) != 0) continue;
    int iy = dy / S; if (iy >= Hin) continue;
    int wky = K - 1 - ky;
    for (int kx = 0; kx < K; kx++){
      int dx = x + kx - PP;
      if (dx < 0 || (dx % S) != 0) continue;
      int ix = dx / S; if (ix >= Win) continue;
      int wkx = K - 1 - kx;
      const float* ip = in + (long long)b*Cin*Hin*Win + (long long)iy*Win + ix;
      for (int c = 0; c < Cin; c++){
        acc += w[(((long long)c*Cout + o)*K + wky)*K + wkx] * ip[(long long)c*Hin*Win];
      }
    }
  }
  if (do_elu) acc = eluf(acc);
  out[idx] = acc;
}

// ---------------- final bicubic warp ----------------
__device__ __forceinline__ float cubicf(float A, float Bv, float C, float D, float t){
  float a = -0.5f*A + 1.5f*Bv - 1.5f*C + 0.5f*D;
  float b =  A - 2.5f*Bv + 2.0f*C - 0.5f*D;
  float c = -0.5f*A + 0.5f*C;
  return ((a*t + b)*t + c)*t + Bv;
}

__global__ void warp_kernel(const float* __restrict__ V, const float* __restrict__ x1,
                            float* __restrict__ out, int B)
{
  int idx = blockIdx.x*256 + threadIdx.x;
  int total = B*784;
  if (idx >= total) return;
  int j = idx % 28; int t = idx / 28;
  int i = t % 28;   int b = t / 28;
  float v0 = V[((long long)b*2 + 0)*784 + j*28 + i];
  float v1 = V[((long long)b*2 + 1)*784 + j*28 + i];
  float gx = (-1.f + 2.f*(float)j/27.f) + v0;
  float gy = (-1.f + 2.f*(float)i/27.f) + v1;
  float ix = (gx + 1.f)*13.5f;
  float iy = (gy + 1.f)*13.5f;
  float x0 = floorf(ix), y0 = floorf(iy);
  float tx = ix - x0, ty = iy - y0;
  const float* img = x1 + (long long)b*2*784;
  float rows[4];
  #pragma unroll
  for (int ky = -1; ky <= 2; ky++){
    int yi = (int)fminf(fmaxf(y0 + (float)ky, 0.f), 27.f);
    float cv[4];
    #pragma unroll
    for (int kx = -1; kx <= 2; kx++){
      int xi = (int)fminf(fmaxf(x0 + (float)kx, 0.f), 27.f);
      cv[kx+1] = img[yi*28 + xi];
    }
    rows[ky+1] = cubicf(cv[0], cv[1], cv[2], cv[3], tx);
  }
  out[idx] = cubicf(rows[0], rows[1], rows[2], rows[3], ty);
}

// ---------------- host ----------------
extern "C" void kernel_launch(void* const* d_in, const int* in_sizes, int n_in,
                              void* d_out, int out_size, void* d_ws, size_t ws_size,
                              hipStream_t stream)
{
  const int B = 256;
  const float* x1      = (const float*)d_in[0];
  const float* conv1_w = (const float*)d_in[9];
  const float* conv1_b = (const float*)d_in[10];
  const float* bn1_g   = (const float*)d_in[11];
  const float* bn1_b   = (const float*)d_in[12];
  const float* dc2_pw  = (const float*)d_in[13];
  const float* dc2_pb  = (const float*)d_in[14];
  const float* dc2_mw  = (const float*)d_in[15];
  const float* dc2_mb  = (const float*)d_in[16];
  const float* dc2_w   = (const float*)d_in[17];
  const float* bn2_g   = (const float*)d_in[18];
  const float* bn2_b   = (const float*)d_in[19];
  const float* conv3_w = (const float*)d_in[20];
  const float* conv3_b = (const float*)d_in[21];
  const float* bn3_g   = (const float*)d_in[22];
  const float* bn3_b   = (const float*)d_in[23];
  const float* dc41_pw = (const float*)d_in[24];
  const float* dc41_pb = (const float*)d_in[25];
  const float* dc41_mw = (const float*)d_in[26];
  const float* dc41_mb = (const float*)d_in[27];
  const float* dc41_w  = (const float*)d_in[28];
  const float* bn41_g  = (const float*)d_in[29];
  const float* bn41_b  = (const float*)d_in[30];
  const float* conv4_w = (const float*)d_in[31];
  const float* conv4_b = (const float*)d_in[32];
  const float* conv4m_w= (const float*)d_in[33];
  const float* conv4m_b= (const float*)d_in[34];
  const float* conv3m_w= (const float*)d_in[35];
  const float* conv3m_b= (const float*)d_in[36];
  const float* conv2m_w= (const float*)d_in[37];
  const float* conv2m_b= (const float*)d_in[38];
  const float* conv1m_w= (const float*)d_in[39];
  const float* conv1m_b= (const float*)d_in[40];

  float* ws = (float*)d_ws;

  // lifetime-packed arena (floats), stats in [0,1024). (R15-R22 layout — verified)
  // t3part (3,686,400 floats) parked at t2m base: t2m written step 14, after combine reads it.
  const long long AB = 1024;
  float* p1   = ws + AB;
  float* a1   = ws + AB + 3211264;
  float* om2  = ws + AB + 3211264;
  float* a2   = ws + AB + 4566016;
  float* a3   = ws + AB + 10988544;
  float* p2   = ws + AB;
  float* om41 = ws + AB + 1605632;
  float* a41  = ws + AB + 1944320;
  float* a4   = ws + AB + 2747136;
  float* t4m  = ws + AB + 2772224;
  float* t3m  = ws + AB + 8310016;
  float* t2m  = ws + AB + 11996416;
  float* t3part = ws + AB + 11996416;   // live only during step [13..13.5]
  float* t1m  = ws + AB;
  float* wT2  = ws + AB + 17411072;
  float* wT41 = ws + AB + 17484800;
  float* wT3m = ws + AB + 17705984;
  unsigned short* wb3 = (unsigned short*)(ws + AB + 17779712);

  float* s1  = ws + 0;   float* q1  = ws + 64;
  float* s2  = ws + 128; float* q2  = ws + 256;
  float* s3  = ws + 384; float* q3  = ws + 512;
  float* s41 = ws + 640; float* q41 = ws + 704;

  auto nb = [](long long n){ return (int)((n + 255)/256); };

  hipMemsetAsync(d_ws, 0, 4096, stream);

  // weight pre-transposes / packs
  wtrans_kernel<<<nb(73728), 256, 0, stream>>>(dc2_w,  wT2,  64, 128);
  wtrans_kernel<<<nb(73728), 256, 0, stream>>>(dc41_w, wT41, 128, 64);
  wtrans3_kernel<<<nb(73728), 256, 0, stream>>>(conv3m_w, wT3m, 128, 64, 1);
  wconv3_bf16_kernel<<<nb(147456), 256, 0, stream>>>(conv3_w, wb3);

  // [1] conv1 (2->64, 28x28), fused bn1 stats
  conv1_tiled<<<dim3(B,8), 256, 0, stream>>>(x1, conv1_w, conv1_b, a1, s1, q1);
  // [2] bn1 + elu + avgpool -> p1
  bn_elu_pool_kernel<<<nb((long long)B*64*196), 256, 0, stream>>>(a1, bn1_g, bn1_b, s1, q1, p1,
                                                                  B, 64, 28, 28, 1.f/200704.f);
  // [3] dc2 offsets (64->18) + mask (64->9, sigmoid) -> om2
  conv_tiled<14,14,14,14,1><<<dim3(B,2), 256, 0, stream>>>(p1, dc2_pw, dc2_pb, om2,
                                                           64, 18, 27, 0, 0);
  conv_tiled<14,14,14,14,1><<<dim3(B,1), 256, 0, stream>>>(p1, dc2_mw, dc2_mb, om2,
                                                           64, 9, 27, 18, 1);
  // [4] deform conv 2 (64->128) -> a2, fused bn2 stats; 4o x 8px register tile (R17-proven)
  deform_gemm<64,128,14,14,49,32,8,128,false><<<dim3(B*4,1), 256, 0, stream>>>(p1, om2, wT2, a2, s2, q2);
  // [5] bn2 + elu
  bn_elu_inplace_kernel<<<nb((long long)B*128*196), 256, 0, stream>>>(a2, bn2_g, bn2_b, s2, q2,
                                                                      128, 196, 1.f/50176.f, B*128*196);
  // [6] conv3 (128->128) -> a3 via bf16 MFMA, fused bn3 stats
  conv3_mfma<<<dim3(B,8), 256, 0, stream>>>(a2, wb3, conv3_b, a3, s3, q3);
  // [7] bn3 + elu + avgpool -> p2
  bn_elu_pool_kernel<<<nb((long long)B*128*49), 256, 0, stream>>>(a3, bn3_g, bn3_b, s3, q3, p2,
                                                                  B, 128, 14, 14, 1.f/50176.f);
  // [8] dc41 offsets + mask -> om41
  conv_tiled<7,7,7,7,1><<<dim3(B,2), 256, 0, stream>>>(p2, dc41_pw, dc41_pb, om41,
                                                       128, 18, 27, 0, 0);
  conv_tiled<7,7,7,7,1><<<dim3(B,1), 256, 0, stream>>>(p2, dc41_mw, dc41_mb, om41,
                                                       128, 9, 27, 18, 1);
  // [9] deform conv 41 (128->64) -> a41, fused bn41 stats; o-split x2 + fp32 LDS weight stage
  deform_gemm<128,64,7,7,49,8,32,32,true><<<dim3(B,2), 256, 0, stream>>>(p2, om41, wT41, a41, s41, q41);
  // [10] bn41 + elu
  bn_elu_inplace_kernel<<<nb((long long)B*64*49), 256, 0, stream>>>(a41, bn41_g, bn41_b, s41, q41,
                                                                    64, 49, 1.f/12544.f, B*64*49);
  // [11] conv4 (64->2, 7x7) naive (tiny)
  conv3x3_kernel<<<nb((long long)B*2*49), 256, 0, stream>>>(a41, conv4_w, conv4_b, a4,
                                                            B, 64, 2, 7, 7, 2, 0, 0);
  // [12] convT4m: 2->128, s=2, p=1, 7->13, parity-decomposed
  convt_s2_tiled<7,7,2,128,false><<<dim3(B,8), 256, 0, stream>>>(a4, conv4m_w, conv4m_b, t4m);
  // [13] convT3m: 128->64, channel-split x2 (4 blocks/CU); z=0 -> t3m (+bias), z=1 -> t3part
  conv_tiled_w2<13,13,15,15,2,2,2><<<dim3(B,2,2), 256, 0, stream>>>(t4m, wT3m, conv3m_b,
                                                                    t3m, t3part, 128, 64);
  // [13.5] combine + elu
  add_elu_kernel<<<nb(3686400), 256, 0, stream>>>(t3m, t3part, 3686400);
  // [14] convT2m: 64->32, s=2, p=1, 15->29, +elu, parity-decomposed
  convt_s2_tiled<15,15,64,32,true><<<dim3(B,2), 256, 0, stream>>>(t3m, conv2m_w, conv2m_b, t2m);
  // [15] convT1m: 32->2, k=2, s=1, p=1, 29->28, +elu (naive, tiny)
  convt_kernel<<<nb((long long)B*2*784), 256, 0, stream>>>(t2m, conv1m_w, conv1m_b, t1m,
                                                           B, 32, 2, 29, 29, 28, 28, 2, 1, 0, 1);
  // [16] final warp
  warp_kernel<<<nb((long long)B*784), 256, 0, stream>>>(t1m, x1, (float*)d_out, B);
}